// Round 4
// baseline (1285.823 us; speedup 1.0000x reference)
//
#include <hip/hip_runtime.h>
#include <cstddef>

#define N_NODES 50000
#define N_EDGES 800000
#define N_PAIRS 100000

typedef short short8 __attribute__((ext_vector_type(8)));
typedef float floatx4 __attribute__((ext_vector_type(4)));
typedef unsigned short ushort_t;

__device__ inline ushort_t f2bf(float x) {
  unsigned u = __float_as_uint(x);
  u += 0x7FFF + ((u >> 16) & 1);  // RNE
  return (ushort_t)(u >> 16);
}
__device__ inline float bf2f(ushort_t h) {
  return __uint_as_float(((unsigned)h) << 16);
}
// packed MFMA A/B-fragment layout: [tile16][kchunk32][lane][8]
__device__ inline size_t packA(int m, int k, int K) {
  return ((size_t)((m >> 4) * (K >> 5) + (k >> 5)) << 9) +
         ((((unsigned)k >> 3) & 3) << 7) + ((m & 15) << 3) + (k & 7);
}
__device__ inline void split8(float4 u0, float4 u1, short8& hi, short8& lo) {
  float f[8] = {u0.x, u0.y, u0.z, u0.w, u1.x, u1.y, u1.z, u1.w};
#pragma unroll
  for (int i = 0; i < 8; i++) {
    ushort_t hh = f2bf(f[i]);
    hi[i] = (short)hh;
    lo[i] = (short)f2bf(f[i] - bf2f(hh));
  }
}

// ---------------- all-in-one weight prep (fold + transpose + split + pack)
__device__ inline float fold_val(int l, int r, int j, const float* Wk, const float* Wq,
                                 const float* Wv, const float* att, const float* msg,
                                 const float* pri) {
  if (j >= 128 && j < 256) return Wq[(l * 128 + r) * 128 + (j - 128)];
  int jj = j & 127, hh = jj >> 4, e = jj & 15;
  const float* W = (j < 128) ? Wk : Wv;
  const float* T = (j < 128) ? att : msg;
  float s = 0.f;
#pragma unroll
  for (int d = 0; d < 16; d++)
    s += W[(l * 128 + r) * 128 + hh * 16 + d] * T[((l * 8 + hh) * 16 + d) * 16 + e];
  if (j < 128) s *= pri[l * 8 + hh] * 0.25f;
  return s;
}

__global__ void wprep_kernel(const float* __restrict__ W_in, const float* __restrict__ Wk,
                             const float* __restrict__ Wq, const float* __restrict__ Wv,
                             const float* __restrict__ att, const float* __restrict__ msg,
                             const float* __restrict__ pri, const float* __restrict__ Wa,
                             const float* __restrict__ W1, const float* __restrict__ W2,
                             ushort_t* Wint_h, ushort_t* Wint_l,
                             ushort_t* Wcat_h, ushort_t* Wcat_l,
                             ushort_t* Wa_h, ushort_t* Wa_l,
                             ushort_t* W1_h, ushort_t* W1_l,
                             ushort_t* W2_h, ushort_t* W2_l) {
  int gid = blockIdx.x * 256 + threadIdx.x;
  float v;
  ushort_t *dh, *dl;
  size_t o;
  if (gid < 16384) {
    int n = gid >> 7, k = gid & 127;
    v = W_in[k * 128 + n];
    dh = Wint_h; dl = Wint_l; o = packA(n, k, 128);
  } else if (gid < 163840) {
    int t = gid - 16384;
    int l = t / 49152, u = t - l * 49152;
    int n = u >> 7, k = u & 127;
    v = fold_val(l, k, n, Wk, Wq, Wv, att, msg, pri);
    dh = Wcat_h + (size_t)l * 49152; dl = Wcat_l + (size_t)l * 49152;
    o = packA(n, k, 128);
  } else if (gid < 212992) {
    int t = gid - 163840;
    int l = t / 16384, u = t & 16383;
    int n = u >> 7, k = u & 127;
    v = Wa[(size_t)l * 16384 + k * 128 + n];
    dh = Wa_h + (size_t)l * 16384; dl = Wa_l + (size_t)l * 16384;
    o = packA(n, k, 128);
  } else if (gid < 221184) {
    int u = gid - 212992;
    int n = u >> 7, k = u & 127;
    v = W1[k * 64 + n];
    dh = W1_h; dl = W1_l; o = packA(n, k, 128);
  } else if (gid < 225280) {
    int u = gid - 221184;
    int n = u >> 6, k = u & 63;
    v = (n < 32) ? W2[k * 32 + n] : 0.f;
    dh = W2_h; dl = W2_l; o = packA(n, k, 64);
  } else {
    return;
  }
  ushort_t hh = f2bf(v);
  dh[o] = hh;
  dl[o] = f2bf(v - bf2f(hh));
}

// ---------------- CSR build (padded to multiple of 8 per node)
__global__ void hist_kernel(const int* __restrict__ dst, int* __restrict__ deg, int E) {
  int g = blockIdx.x * blockDim.x + threadIdx.x;
  if (g < E) atomicAdd(&deg[dst[g]], 1);
}

__global__ void scanA_kernel(const int* __restrict__ deg, int* __restrict__ offs,
                             int* __restrict__ bsum, int n) {
  __shared__ int sm[256];
  int t = threadIdx.x;
  int i = blockIdx.x * 256 + t;
  int v = (i < n) ? ((deg[i] + 7) & ~7) : 0;
  sm[t] = v;
  __syncthreads();
  for (int off = 1; off < 256; off <<= 1) {
    int u = (t >= off) ? sm[t - off] : 0;
    __syncthreads();
    sm[t] += u;
    __syncthreads();
  }
  if (i < n) offs[i] = sm[t] - v;
  if (t == 255) bsum[blockIdx.x] = sm[255];
}

__global__ void scanB_kernel(const int* __restrict__ bsum, int* __restrict__ boff,
                             int* __restrict__ offs, int nb, int n) {
  __shared__ int sm[256];
  int t = threadIdx.x;
  int v = (t < nb) ? bsum[t] : 0;
  sm[t] = v;
  __syncthreads();
  for (int off = 1; off < 256; off <<= 1) {
    int u = (t >= off) ? sm[t - off] : 0;
    __syncthreads();
    sm[t] += u;
    __syncthreads();
  }
  boff[t] = sm[t] - v;
  if (t == nb - 1) offs[n] = sm[t];
}

__global__ void scanC_kernel(int* __restrict__ offs, const int* __restrict__ boff,
                             int* __restrict__ cursor, int n) {
  int i = blockIdx.x * 256 + threadIdx.x;
  if (i < n) {
    int o = offs[i] + boff[blockIdx.x];
    offs[i] = o;
    cursor[i] = o;
  }
}

__global__ void scatter_kernel(const int* __restrict__ src, const int* __restrict__ dst,
                               const float* __restrict__ w, int* __restrict__ cursor,
                               int2* __restrict__ eld, int E) {
  int g = blockIdx.x * blockDim.x + threadIdx.x;
  if (g < E) {
    int d = dst[g];
    int p = atomicAdd(&cursor[d], 1);
    eld[p] = make_int2(src[g], __float_as_int(w[g]));
  }
}

// ---------------- degree-descending node permutation (counting sort, 256 buckets)
__global__ void bhist_kernel(const int* __restrict__ deg, int* __restrict__ bh, int n) {
  int i = blockIdx.x * 256 + threadIdx.x;
  if (i < n) atomicAdd(&bh[min(deg[i], 255)], 1);
}
__global__ void bscan_kernel(const int* __restrict__ bh, int* __restrict__ bcur) {
  __shared__ int sm[256];
  int t = threadIdx.x;
  int v = bh[255 - t];
  sm[t] = v;
  __syncthreads();
  for (int off = 1; off < 256; off <<= 1) {
    int u = (t >= off) ? sm[t - off] : 0;
    __syncthreads();
    sm[t] += u;
    __syncthreads();
  }
  bcur[255 - t] = sm[t] - v;
}
__global__ void bscatter_kernel(const int* __restrict__ deg, int* __restrict__ bcur,
                                int* __restrict__ perm, int n) {
  int i = blockIdx.x * 256 + threadIdx.x;
  if (i < n) {
    int slot = atomicAdd(&bcur[min(deg[i], 255)], 1);
    perm[slot] = i;
  }
}

// ---------------- split-bf16 MFMA GEMM
// AMODE: 0 = packed hi/lo A; 1 = fp32 row-major A (split on the fly);
//        2 = pair-product gather A = hsrc[ia[r]] * hsrc[ib[r]] (predictor)
// CFG: 0 = 2x2 waves (block 128m x 128n); 1 = 4x1 waves (block 256m x 64n)
// epi: 0 bias+relu, 1 plain, 2 skip-mix(+relu), 3 bias+leaky, 4 bias+leaky+dot(W3)+b3 -> outd
template <int AMODE, int CFG>
__global__ __launch_bounds__(256) void gemm_mfma(
    const ushort_t* __restrict__ Ah, const ushort_t* __restrict__ Al,
    const float* __restrict__ Af, const float* __restrict__ hsrc,
    const int* __restrict__ psrc, const int* __restrict__ pdst,
    const int* __restrict__ nsrc, const int* __restrict__ ndst,
    const ushort_t* __restrict__ Bth, const ushort_t* __restrict__ Btl,
    int M, int N, int K, int epi,
    const float* __restrict__ bias,
    const ushort_t* __restrict__ hold_hi, const ushort_t* __restrict__ hold_lo,
    const float* __restrict__ skipv, int relu,
    float* __restrict__ Cf, ushort_t* __restrict__ Chi, ushort_t* __restrict__ Clo,
    int Kout, const float* __restrict__ W3, const float* __restrict__ b3,
    float* __restrict__ outd) {
  int tid = threadIdx.x;
  int wave = tid >> 6, lane = tid & 63;
  int l16 = lane & 15, q = lane >> 4;
  int m_base, n_base;
  if (CFG == 0) {
    m_base = blockIdx.x * 128 + (wave >> 1) * 64;
    n_base = blockIdx.y * 128 + (wave & 1) * 64;
  } else {
    m_base = blockIdx.x * 256 + wave * 64;
    n_base = 0;
  }
  int kc_count = K >> 5;

  floatx4 acc[4][4];
#pragma unroll
  for (int i = 0; i < 4; i++)
#pragma unroll
    for (int j = 0; j < 4; j++) acc[i][j] = (floatx4){0.f, 0.f, 0.f, 0.f};

  bool tv[4];
  size_t a_base[4];
  int rowA[4], pa[4], pb[4];
#pragma unroll
  for (int mt = 0; mt < 4; mt++) {
    int tile = (m_base >> 4) + mt;
    tv[mt] = (tile * 16) < M;
    if (AMODE == 0) {
      a_base[mt] = ((size_t)(tv[mt] ? tile : 0) * kc_count << 9) + lane * 8;
    } else if (AMODE == 1) {
      rowA[mt] = min(m_base + mt * 16 + l16, M - 1);
    } else {
      int gr = min(m_base + mt * 16 + l16, M - 1);
      bool pos = gr < N_PAIRS;
      int idx = pos ? gr : gr - N_PAIRS;
      pa[mt] = pos ? psrc[idx] : nsrc[idx];
      pb[mt] = pos ? pdst[idx] : ndst[idx];
    }
  }
  size_t b_base[4];
#pragma unroll
  for (int nt = 0; nt < 4; nt++)
    b_base[nt] = ((size_t)((n_base >> 4) + nt) * kc_count << 9) + lane * 8;

  const short8 zer = {0, 0, 0, 0, 0, 0, 0, 0};
  for (int kc = 0; kc < kc_count; kc++) {
    size_t koff = (size_t)kc << 9;
    int kbase = kc * 32 + q * 8;
    short8 b_h[4], b_l[4];
#pragma unroll
    for (int nt = 0; nt < 4; nt++) {
      b_h[nt] = *(const short8*)(Bth + b_base[nt] + koff);
      b_l[nt] = *(const short8*)(Btl + b_base[nt] + koff);
    }
    short8 a_h[4], a_l[4];
#pragma unroll
    for (int mt = 0; mt < 4; mt++) {
      if (AMODE == 0) {
        if (tv[mt]) {
          a_h[mt] = *(const short8*)(Ah + a_base[mt] + koff);
          a_l[mt] = *(const short8*)(Al + a_base[mt] + koff);
        } else {
          a_h[mt] = zer;
          a_l[mt] = zer;
        }
      } else if (AMODE == 1) {
        const float* p = Af + (size_t)rowA[mt] * K + kbase;
        split8(*(const float4*)p, *(const float4*)(p + 4), a_h[mt], a_l[mt]);
      } else {
        const float* ra = hsrc + (size_t)pa[mt] * K + kbase;
        const float* rb = hsrc + (size_t)pb[mt] * K + kbase;
        float4 a0 = *(const float4*)ra, a1 = *(const float4*)(ra + 4);
        float4 c0 = *(const float4*)rb, c1 = *(const float4*)(rb + 4);
        float4 z0 = make_float4(a0.x * c0.x, a0.y * c0.y, a0.z * c0.z, a0.w * c0.w);
        float4 z1 = make_float4(a1.x * c1.x, a1.y * c1.y, a1.z * c1.z, a1.w * c1.w);
        split8(z0, z1, a_h[mt], a_l[mt]);
      }
    }
#pragma unroll
    for (int mt = 0; mt < 4; mt++)
#pragma unroll
      for (int nt = 0; nt < 4; nt++) {
        acc[mt][nt] = __builtin_amdgcn_mfma_f32_16x16x32_bf16(a_h[mt], b_h[nt], acc[mt][nt], 0, 0, 0);
        acc[mt][nt] = __builtin_amdgcn_mfma_f32_16x16x32_bf16(a_h[mt], b_l[nt], acc[mt][nt], 0, 0, 0);
        acc[mt][nt] = __builtin_amdgcn_mfma_f32_16x16x32_bf16(a_l[mt], b_h[nt], acc[mt][nt], 0, 0, 0);
      }
  }

  if (epi == 4) {
    float b3v = b3[0];
#pragma unroll
    for (int mt = 0; mt < 4; mt++) {
      if (!tv[mt]) continue;
#pragma unroll
      for (int r = 0; r < 4; r++) {
        int row = m_base + mt * 16 + q * 4 + r;
        if (row >= M) continue;
        float partial = 0.f;
#pragma unroll
        for (int nt = 0; nt < 4; nt++) {
          int col = n_base + nt * 16 + l16;
          if (col < N) {
            float v = acc[mt][nt][r] + bias[col];
            v = v > 0.f ? v : 0.2f * v;
            partial += v * W3[col];
          }
        }
        partial += __shfl_xor(partial, 1);
        partial += __shfl_xor(partial, 2);
        partial += __shfl_xor(partial, 4);
        partial += __shfl_xor(partial, 8);
        if (l16 == 0) outd[row] = partial + b3v;
      }
    }
    return;
  }

  float alpha = 1.f, beta = 0.f;
  if (epi == 2) {
    float s = *skipv;
    alpha = 1.f / (1.f + __expf(-s));
    beta = 1.f - alpha;
  }
#pragma unroll
  for (int mt = 0; mt < 4; mt++) {
#pragma unroll
    for (int nt = 0; nt < 4; nt++) {
      int col = n_base + nt * 16 + l16;
      if (col >= N) continue;
      float bv = (epi == 0 || epi == 3) ? bias[col] : 0.f;
#pragma unroll
      for (int r = 0; r < 4; r++) {
        int row = m_base + mt * 16 + q * 4 + r;
        if (row >= M) continue;
        float v = acc[mt][nt][r];
        if (epi == 0) {
          v = fmaxf(v + bv, 0.f);
        } else if (epi == 2) {
          size_t ho = packA(row, col, 128);
          float hv = bf2f(hold_hi[ho]) + bf2f(hold_lo[ho]);
          v = alpha * v + beta * hv;
          if (relu) v = fmaxf(v, 0.f);
        } else if (epi == 3) {
          v += bv;
          v = v > 0.f ? v : 0.2f * v;
        }
        if (Cf) Cf[(size_t)row * N + col] = v;
        if (Chi) {
          ushort_t hh = f2bf(v);
          size_t o = packA(row, col, Kout);
          Chi[o] = hh;
          Clo[o] = f2bf(v - bf2f(hh));
        }
      }
    }
  }
}

// ---------------- per-destination online-softmax aggregation, padded 8-edge batches
__global__ __launch_bounds__(256) void edge_agg_kernel(
    const float* __restrict__ kqv, const int* __restrict__ poffs,
    const int2* __restrict__ eld, const int* __restrict__ perm,
    ushort_t* __restrict__ agg_hi, ushort_t* __restrict__ agg_lo, int n) {
  int gw = blockIdx.x * 4 + (threadIdx.x >> 6);
  if (gw >= n) return;
  int node = perm[gw];
  int lane = threadIdx.x & 63;
  int c2 = lane & 31, half = lane >> 5;
  int ch = c2 << 2;
  float4 qv = *(const float4*)&kqv[(size_t)node * 384 + 128 + ch];
  int off_half = (half ? 256 : 0) + ch;
  float m = -1e30f, s = 0.f;
  float ax = 0.f, ay = 0.f, az = 0.f, aw = 0.f;
  int j = poffs[node], end = poffs[node + 1];
  for (; j < end; j += 8) {
    int2 e0 = eld[j + 0], e1 = eld[j + 1], e2 = eld[j + 2], e3 = eld[j + 3];
    int2 e4 = eld[j + 4], e5 = eld[j + 5], e6 = eld[j + 6], e7 = eld[j + 7];
    float4 g0 = *(const float4*)&kqv[(size_t)max(e0.x, 0) * 384 + off_half];
    float4 g1 = *(const float4*)&kqv[(size_t)max(e1.x, 0) * 384 + off_half];
    float4 g2 = *(const float4*)&kqv[(size_t)max(e2.x, 0) * 384 + off_half];
    float4 g3 = *(const float4*)&kqv[(size_t)max(e3.x, 0) * 384 + off_half];
    float4 g4 = *(const float4*)&kqv[(size_t)max(e4.x, 0) * 384 + off_half];
    float4 g5 = *(const float4*)&kqv[(size_t)max(e5.x, 0) * 384 + off_half];
    float4 g6 = *(const float4*)&kqv[(size_t)max(e6.x, 0) * 384 + off_half];
    float4 g7 = *(const float4*)&kqv[(size_t)max(e7.x, 0) * 384 + off_half];
    float p0 = g0.x * qv.x + g0.y * qv.y + g0.z * qv.z + g0.w * qv.w;
    float p1 = g1.x * qv.x + g1.y * qv.y + g1.z * qv.z + g1.w * qv.w;
    float p2 = g2.x * qv.x + g2.y * qv.y + g2.z * qv.z + g2.w * qv.w;
    float p3 = g3.x * qv.x + g3.y * qv.y + g3.z * qv.z + g3.w * qv.w;
    float p4 = g4.x * qv.x + g4.y * qv.y + g4.z * qv.z + g4.w * qv.w;
    float p5 = g5.x * qv.x + g5.y * qv.y + g5.z * qv.z + g5.w * qv.w;
    float p6 = g6.x * qv.x + g6.y * qv.y + g6.z * qv.z + g6.w * qv.w;
    float p7 = g7.x * qv.x + g7.y * qv.y + g7.z * qv.z + g7.w * qv.w;
    p0 = e0.x >= 0 ? p0 : -1e30f;
    p1 = e1.x >= 0 ? p1 : -1e30f;
    p2 = e2.x >= 0 ? p2 : -1e30f;
    p3 = e3.x >= 0 ? p3 : -1e30f;
    p4 = e4.x >= 0 ? p4 : -1e30f;
    p5 = e5.x >= 0 ? p5 : -1e30f;
    p6 = e6.x >= 0 ? p6 : -1e30f;
    p7 = e7.x >= 0 ? p7 : -1e30f;
    p0 += __shfl_xor(p0, 1); p1 += __shfl_xor(p1, 1);
    p2 += __shfl_xor(p2, 1); p3 += __shfl_xor(p3, 1);
    p4 += __shfl_xor(p4, 1); p5 += __shfl_xor(p5, 1);
    p6 += __shfl_xor(p6, 1); p7 += __shfl_xor(p7, 1);
    p0 += __shfl_xor(p0, 2); p1 += __shfl_xor(p1, 2);
    p2 += __shfl_xor(p2, 2); p3 += __shfl_xor(p3, 2);
    p4 += __shfl_xor(p4, 2); p5 += __shfl_xor(p5, 2);
    p6 += __shfl_xor(p6, 2); p7 += __shfl_xor(p7, 2);
    float o0 = __shfl_xor(p0, 32), o1 = __shfl_xor(p1, 32);
    float o2 = __shfl_xor(p2, 32), o3 = __shfl_xor(p3, 32);
    float o4 = __shfl_xor(p4, 32), o5 = __shfl_xor(p5, 32);
    float o6 = __shfl_xor(p6, 32), o7 = __shfl_xor(p7, 32);
    if (half) { p0 = o0; p1 = o1; p2 = o2; p3 = o3; p4 = o4; p5 = o5; p6 = o6; p7 = o7; }
    float nm = fmaxf(m, fmaxf(fmaxf(fmaxf(p0, p1), fmaxf(p2, p3)),
                              fmaxf(fmaxf(p4, p5), fmaxf(p6, p7))));
    float sc = __expf(m - nm);
    float t0 = __expf(p0 - nm), t1 = __expf(p1 - nm);
    float t2 = __expf(p2 - nm), t3 = __expf(p3 - nm);
    float t4 = __expf(p4 - nm), t5 = __expf(p5 - nm);
    float t6 = __expf(p6 - nm), t7 = __expf(p7 - nm);
    s = s * sc + (((t0 + t1) + (t2 + t3)) + ((t4 + t5) + (t6 + t7)));
    if (half) {
      float w0 = e0.x >= 0 ? __int_as_float(e0.y) : 0.f;
      float w1 = e1.x >= 0 ? __int_as_float(e1.y) : 0.f;
      float w2 = e2.x >= 0 ? __int_as_float(e2.y) : 0.f;
      float w3 = e3.x >= 0 ? __int_as_float(e3.y) : 0.f;
      float w4 = e4.x >= 0 ? __int_as_float(e4.y) : 0.f;
      float w5 = e5.x >= 0 ? __int_as_float(e5.y) : 0.f;
      float w6 = e6.x >= 0 ? __int_as_float(e6.y) : 0.f;
      float w7 = e7.x >= 0 ? __int_as_float(e7.y) : 0.f;
      float f0 = t0 * w0, f1 = t1 * w1, f2 = t2 * w2, f3 = t3 * w3;
      float f4 = t4 * w4, f5 = t5 * w5, f6 = t6 * w6, f7 = t7 * w7;
      ax = ax * sc + ((f0 * g0.x + f1 * g1.x) + (f2 * g2.x + f3 * g3.x)) +
           ((f4 * g4.x + f5 * g5.x) + (f6 * g6.x + f7 * g7.x));
      ay = ay * sc + ((f0 * g0.y + f1 * g1.y) + (f2 * g2.y + f3 * g3.y)) +
           ((f4 * g4.y + f5 * g5.y) + (f6 * g6.y + f7 * g7.y));
      az = az * sc + ((f0 * g0.z + f1 * g1.z) + (f2 * g2.z + f3 * g3.z)) +
           ((f4 * g4.z + f5 * g5.z) + (f6 * g6.z + f7 * g7.z));
      aw = aw * sc + ((f0 * g0.w + f1 * g1.w) + (f2 * g2.w + f3 * g3.w)) +
           ((f4 * g4.w + f5 * g5.w) + (f6 * g6.w + f7 * g7.w));
    }
    m = nm;
  }
  if (half) {
    float inv = (s > 0.f) ? 1.f / s : 0.f;
    float v0 = ax * inv, v1 = ay * inv, v2 = az * inv, v3 = aw * inv;
    ushort_t h0 = f2bf(v0), h1 = f2bf(v1), h2 = f2bf(v2), h3 = f2bf(v3);
    size_t base = packA(node, ch, 128);
    *(uint2*)(agg_hi + base) = make_uint2((unsigned)h0 | ((unsigned)h1 << 16),
                                          (unsigned)h2 | ((unsigned)h3 << 16));
    ushort_t l0 = f2bf(v0 - bf2f(h0)), l1 = f2bf(v1 - bf2f(h1));
    ushort_t l2 = f2bf(v2 - bf2f(h2)), l3 = f2bf(v3 - bf2f(h3));
    *(uint2*)(agg_lo + base) = make_uint2((unsigned)l0 | ((unsigned)l1 << 16),
                                          (unsigned)l2 | ((unsigned)l3 << 16));
  }
}

extern "C" void kernel_launch(void* const* d_in, const int* in_sizes, int n_in,
                              void* d_out, int out_size, void* d_ws, size_t ws_size,
                              hipStream_t stream) {
  const float* x        = (const float*)d_in[0];
  const int*   edge_src = (const int*)d_in[1];
  const int*   edge_dst = (const int*)d_in[2];
  const float* edge_w   = (const float*)d_in[3];
  const int*   pos_src  = (const int*)d_in[4];
  const int*   pos_dst  = (const int*)d_in[5];
  const int*   neg_src  = (const int*)d_in[6];
  const int*   neg_dst  = (const int*)d_in[7];
  const float* W_in     = (const float*)d_in[8];
  const float* b_in     = (const float*)d_in[9];
  const float* Wk       = (const float*)d_in[10];
  const float* Wq       = (const float*)d_in[11];
  const float* Wv       = (const float*)d_in[12];
  const float* att_w    = (const float*)d_in[13];
  const float* msg_w    = (const float*)d_in[14];
  const float* pri      = (const float*)d_in[15];
  const float* Wa       = (const float*)d_in[16];
  const float* skip     = (const float*)d_in[17];
  const float* W1       = (const float*)d_in[18];
  const float* b1       = (const float*)d_in[19];
  const float* W2       = (const float*)d_in[20];
  const float* b2       = (const float*)d_in[21];
  const float* W3       = (const float*)d_in[22];
  const float* b3       = (const float*)d_in[23];
  float* out = (float*)d_out;

  // ---- workspace layout (bytes), ~139.5 MB
  char* W = (char*)d_ws;
  float*    kqv    = (float*)(W + 0);             // 76,800,000
  ushort_t* h_hi   = (ushort_t*)(W + 76800000);   // 12,800,000
  ushort_t* h_lo   = (ushort_t*)(W + 89600000);   // 12,800,000
  ushort_t* agg_hi = (ushort_t*)(W + 102400000);  // 12,800,000
  ushort_t* agg_lo = (ushort_t*)(W + 115200000);  // 12,800,000
  ushort_t* Wint_h = (ushort_t*)(W + 128000000);  // 32,768
  ushort_t* Wint_l = (ushort_t*)(W + 128032768);  // 32,768
  ushort_t* Wcat_h = (ushort_t*)(W + 128065536);  // 294,912
  ushort_t* Wcat_l = (ushort_t*)(W + 128360448);  // 294,912
  ushort_t* Wa_h   = (ushort_t*)(W + 128655360);  // 98,304
  ushort_t* Wa_l   = (ushort_t*)(W + 128753664);  // 98,304
  ushort_t* W1_h   = (ushort_t*)(W + 128851968);  // 16,384
  ushort_t* W1_l   = (ushort_t*)(W + 128868352);  // 16,384
  ushort_t* W2_h   = (ushort_t*)(W + 128884736);  // 8,192
  ushort_t* W2_l   = (ushort_t*)(W + 128892928);  // 8,192
  int2*     eld    = (int2*)(W + 128901120);      // 9,600,000 (padded edges)
  int*      deg    = (int*)(W + 138501120);       // 200,000
  int*      poffs  = (int*)(W + 138701120);       // 200,016
  int*      cursor = (int*)(W + 138901136);       // 200,000
  int*      perm   = (int*)(W + 139101136);       // 200,000
  int*      bsum   = (int*)(W + 139301136);       // 1,024
  int*      boff   = (int*)(W + 139302160);       // 1,024
  int*      bh     = (int*)(W + 139303184);       // 1,024
  int*      bcur   = (int*)(W + 139304208);       // 1,024
  // aliases (kqv dead by predictor time)
  ushort_t* T1_h = (ushort_t*)(W + 0);            // 25,600,000
  ushort_t* T1_l = (ushort_t*)(W + 25600000);     // 25,600,000
  float* hfinal = out + 2 * N_PAIRS;

  hipMemsetAsync(deg, 0, N_NODES * sizeof(int), stream);
  hipMemsetAsync(bh, 0, 1024, stream);
  hipMemsetAsync(eld, 0xFF, 9600000, stream);  // sentinel: src=-1

  wprep_kernel<<<880, 256, 0, stream>>>(W_in, Wk, Wq, Wv, att_w, msg_w, pri, Wa, W1, W2,
                                        Wint_h, Wint_l, Wcat_h, Wcat_l, Wa_h, Wa_l,
                                        W1_h, W1_l, W2_h, W2_l);
  hist_kernel<<<(N_EDGES + 255) / 256, 256, 0, stream>>>(edge_dst, deg, N_EDGES);
  scanA_kernel<<<196, 256, 0, stream>>>(deg, poffs, bsum, N_NODES);
  scanB_kernel<<<1, 256, 0, stream>>>(bsum, boff, poffs, 196, N_NODES);
  scanC_kernel<<<196, 256, 0, stream>>>(poffs, boff, cursor, N_NODES);
  scatter_kernel<<<(N_EDGES + 255) / 256, 256, 0, stream>>>(
      edge_src, edge_dst, edge_w, cursor, eld, N_EDGES);
  bhist_kernel<<<196, 256, 0, stream>>>(deg, bh, N_NODES);
  bscan_kernel<<<1, 256, 0, stream>>>(bh, bcur);
  bscatter_kernel<<<196, 256, 0, stream>>>(deg, bcur, perm, N_NODES);

  // input projection: h = relu(x @ W_in + b_in) -> packed hi/lo
  gemm_mfma<1, 0><<<dim3(391, 1), 256, 0, stream>>>(
      nullptr, nullptr, x, nullptr, nullptr, nullptr, nullptr, nullptr,
      Wint_h, Wint_l, N_NODES, 128, 128, 0, b_in, nullptr, nullptr, nullptr, 0,
      nullptr, h_hi, h_lo, 128, nullptr, nullptr, nullptr);

  for (int l = 0; l < 3; l++) {
    gemm_mfma<0, 0><<<dim3(391, 3), 256, 0, stream>>>(
        h_hi, h_lo, nullptr, nullptr, nullptr, nullptr, nullptr, nullptr,
        Wcat_h + l * 49152, Wcat_l + l * 49152, N_NODES, 384, 128, 1,
        nullptr, nullptr, nullptr, nullptr, 0, kqv, nullptr, nullptr, 0,
        nullptr, nullptr, nullptr);
    edge_agg_kernel<<<(N_NODES + 3) / 4, 256, 0, stream>>>(
        kqv, poffs, eld, perm, agg_hi, agg_lo, N_NODES);
    int last = (l == 2);
    gemm_mfma<0, 0><<<dim3(391, 1), 256, 0, stream>>>(
        agg_hi, agg_lo, nullptr, nullptr, nullptr, nullptr, nullptr, nullptr,
        Wa_h + l * 16384, Wa_l + l * 16384, N_NODES, 128, 128, 2,
        nullptr, h_hi, h_lo, skip + l, last ? 0 : 1,
        last ? hfinal : nullptr, last ? nullptr : h_hi, last ? nullptr : h_lo, 128,
        nullptr, nullptr, nullptr);
  }

  // predictor: one 200000-row pass (pos | neg), zbuild fused into gemm1, dot fused into gemm2
  gemm_mfma<2, 1><<<dim3(782, 1), 256, 0, stream>>>(
      nullptr, nullptr, nullptr, hfinal, pos_src, pos_dst, neg_src, neg_dst,
      W1_h, W1_l, 2 * N_PAIRS, 64, 128, 3, b1, nullptr, nullptr, nullptr, 0,
      nullptr, T1_h, T1_l, 64, nullptr, nullptr, nullptr);
  gemm_mfma<0, 1><<<dim3(782, 1), 256, 0, stream>>>(
      T1_h, T1_l, nullptr, nullptr, nullptr, nullptr, nullptr, nullptr,
      W2_h, W2_l, 2 * N_PAIRS, 32, 64, 4, b2, nullptr, nullptr, nullptr, 0,
      nullptr, nullptr, nullptr, 0, W3, b3, out);
}

// Round 5
// 876.398 us; speedup vs baseline: 1.4672x; 1.4672x over previous
//
#include <hip/hip_runtime.h>
#include <cstddef>

#define N_NODES 50000
#define N_EDGES 800000
#define N_PAIRS 100000

typedef short short8 __attribute__((ext_vector_type(8)));
typedef float floatx4 __attribute__((ext_vector_type(4)));
typedef _Float16 half4v __attribute__((ext_vector_type(4)));
typedef unsigned short ushort_t;

__device__ inline ushort_t f2bf(float x) {
  unsigned u = __float_as_uint(x);
  u += 0x7FFF + ((u >> 16) & 1);  // RNE
  return (ushort_t)(u >> 16);
}
__device__ inline float bf2f(ushort_t h) {
  return __uint_as_float(((unsigned)h) << 16);
}
// packed MFMA A/B-fragment layout: [tile16][kchunk32][lane][8]
__device__ inline size_t packA(int m, int k, int K) {
  return ((size_t)((m >> 4) * (K >> 5) + (k >> 5)) << 9) +
         ((((unsigned)k >> 3) & 3) << 7) + ((m & 15) << 3) + (k & 7);
}
__device__ inline void split8(float4 u0, float4 u1, short8& hi, short8& lo) {
  float f[8] = {u0.x, u0.y, u0.z, u0.w, u1.x, u1.y, u1.z, u1.w};
#pragma unroll
  for (int i = 0; i < 8; i++) {
    ushort_t hh = f2bf(f[i]);
    hi[i] = (short)hh;
    lo[i] = (short)f2bf(f[i] - bf2f(hh));
  }
}

// ---------------- all-in-one weight prep (fold + transpose + split + pack)
__device__ inline float fold_val(int l, int r, int j, const float* Wk, const float* Wq,
                                 const float* Wv, const float* att, const float* msg,
                                 const float* pri) {
  if (j >= 128 && j < 256) return Wq[(l * 128 + r) * 128 + (j - 128)];
  int jj = j & 127, hh = jj >> 4, e = jj & 15;
  const float* W = (j < 128) ? Wk : Wv;
  const float* T = (j < 128) ? att : msg;
  float s = 0.f;
#pragma unroll
  for (int d = 0; d < 16; d++)
    s += W[(l * 128 + r) * 128 + hh * 16 + d] * T[((l * 8 + hh) * 16 + d) * 16 + e];
  if (j < 128) s *= pri[l * 8 + hh] * 0.25f;
  return s;
}

__global__ void wprep_kernel(const float* __restrict__ W_in, const float* __restrict__ Wk,
                             const float* __restrict__ Wq, const float* __restrict__ Wv,
                             const float* __restrict__ att, const float* __restrict__ msg,
                             const float* __restrict__ pri, const float* __restrict__ Wa,
                             const float* __restrict__ W1, const float* __restrict__ W2,
                             ushort_t* Wint_h, ushort_t* Wint_l,
                             ushort_t* Wcat_h, ushort_t* Wcat_l,
                             ushort_t* Wa_h, ushort_t* Wa_l,
                             ushort_t* W1_h, ushort_t* W1_l,
                             ushort_t* W2_h, ushort_t* W2_l) {
  int gid = blockIdx.x * 256 + threadIdx.x;
  float v;
  ushort_t *dh, *dl;
  size_t o;
  if (gid < 16384) {
    int n = gid >> 7, k = gid & 127;
    v = W_in[k * 128 + n];
    dh = Wint_h; dl = Wint_l; o = packA(n, k, 128);
  } else if (gid < 163840) {
    int t = gid - 16384;
    int l = t / 49152, u = t - l * 49152;
    int n = u >> 7, k = u & 127;
    v = fold_val(l, k, n, Wk, Wq, Wv, att, msg, pri);
    dh = Wcat_h + (size_t)l * 49152; dl = Wcat_l + (size_t)l * 49152;
    o = packA(n, k, 128);
  } else if (gid < 212992) {
    int t = gid - 163840;
    int l = t / 16384, u = t & 16383;
    int n = u >> 7, k = u & 127;
    v = Wa[(size_t)l * 16384 + k * 128 + n];
    dh = Wa_h + (size_t)l * 16384; dl = Wa_l + (size_t)l * 16384;
    o = packA(n, k, 128);
  } else if (gid < 221184) {
    int u = gid - 212992;
    int n = u >> 7, k = u & 127;
    v = W1[k * 64 + n];
    dh = W1_h; dl = W1_l; o = packA(n, k, 128);
  } else if (gid < 225280) {
    int u = gid - 221184;
    int n = u >> 6, k = u & 63;
    v = (n < 32) ? W2[k * 32 + n] : 0.f;
    dh = W2_h; dl = W2_l; o = packA(n, k, 64);
  } else {
    return;
  }
  ushort_t hh = f2bf(v);
  dh[o] = hh;
  dl[o] = f2bf(v - bf2f(hh));
}

// ---------------- CSR build (padded to multiple of 8 per node)
__global__ void hist_kernel(const int* __restrict__ dst, int* __restrict__ deg, int E) {
  int g = blockIdx.x * blockDim.x + threadIdx.x;
  if (g < E) atomicAdd(&deg[dst[g]], 1);
}

__global__ void scanA_kernel(const int* __restrict__ deg, int* __restrict__ offs,
                             int* __restrict__ bsum, int n) {
  __shared__ int sm[256];
  int t = threadIdx.x;
  int i = blockIdx.x * 256 + t;
  int v = (i < n) ? ((deg[i] + 7) & ~7) : 0;
  sm[t] = v;
  __syncthreads();
  for (int off = 1; off < 256; off <<= 1) {
    int u = (t >= off) ? sm[t - off] : 0;
    __syncthreads();
    sm[t] += u;
    __syncthreads();
  }
  if (i < n) offs[i] = sm[t] - v;
  if (t == 255) bsum[blockIdx.x] = sm[255];
}

__global__ void scanB_kernel(const int* __restrict__ bsum, int* __restrict__ boff,
                             int* __restrict__ offs, int nb, int n) {
  __shared__ int sm[256];
  int t = threadIdx.x;
  int v = (t < nb) ? bsum[t] : 0;
  sm[t] = v;
  __syncthreads();
  for (int off = 1; off < 256; off <<= 1) {
    int u = (t >= off) ? sm[t - off] : 0;
    __syncthreads();
    sm[t] += u;
    __syncthreads();
  }
  boff[t] = sm[t] - v;
  if (t == nb - 1) offs[n] = sm[t];
}

__global__ void scanC_kernel(int* __restrict__ offs, const int* __restrict__ boff,
                             int* __restrict__ cursor, int n) {
  int i = blockIdx.x * 256 + threadIdx.x;
  if (i < n) {
    int o = offs[i] + boff[blockIdx.x];
    offs[i] = o;
    cursor[i] = o;
  }
}

__global__ void scatter_kernel(const int* __restrict__ src, const int* __restrict__ dst,
                               const float* __restrict__ w, int* __restrict__ cursor,
                               int2* __restrict__ eld, int E) {
  int g = blockIdx.x * blockDim.x + threadIdx.x;
  if (g < E) {
    int d = dst[g];
    int p = atomicAdd(&cursor[d], 1);
    eld[p] = make_int2(src[g], __float_as_int(w[g]));
  }
}

// ---------------- degree-descending node permutation (counting sort, 256 buckets)
// LDS-aggregated histogram: one global atomic per bucket per block
__global__ void bhist_kernel(const int* __restrict__ deg, int* __restrict__ bh, int n) {
  __shared__ int lh[256];
  int t = threadIdx.x;
  lh[t] = 0;
  __syncthreads();
  int i = blockIdx.x * 256 + t;
  if (i < n) atomicAdd(&lh[min(deg[i], 255)], 1);
  __syncthreads();
  if (lh[t]) atomicAdd(&bh[t], lh[t]);
}
__global__ void bscan_kernel(const int* __restrict__ bh, int* __restrict__ bcur) {
  __shared__ int sm[256];
  int t = threadIdx.x;
  int v = bh[255 - t];
  sm[t] = v;
  __syncthreads();
  for (int off = 1; off < 256; off <<= 1) {
    int u = (t >= off) ? sm[t - off] : 0;
    __syncthreads();
    sm[t] += u;
    __syncthreads();
  }
  bcur[255 - t] = sm[t] - v;
}
// LDS-aggregated two-phase scatter: per-block slot reservation, then local ordering
__global__ void bscatter_kernel(const int* __restrict__ deg, int* __restrict__ bcur,
                                int* __restrict__ perm, int n) {
  __shared__ int lh[256], lbase[256];
  int t = threadIdx.x;
  lh[t] = 0;
  __syncthreads();
  int i = blockIdx.x * 256 + t;
  int b = 0, local = 0;
  if (i < n) {
    b = min(deg[i], 255);
    local = atomicAdd(&lh[b], 1);  // LDS atomic
  }
  __syncthreads();
  int cnt = lh[t];
  lbase[t] = cnt ? atomicAdd(&bcur[t], cnt) : 0;
  __syncthreads();
  if (i < n) perm[lbase[b] + local] = i;
}

// ---------------- split-bf16 MFMA GEMM
// AMODE: 0 = packed hi/lo A; 1 = fp32 row-major A (split on the fly);
//        2 = pair-product gather A = hsrc[ia[r]] * hsrc[ib[r]] (predictor)
// CFG: 0 = 2x2 waves (block 128m x 128n); 1 = 4x1 waves (block 256m x 64n)
// epi: 0 bias+relu, 1 kqv-split-write (kw/mv fp16 + q fp32), 2 skip-mix(+relu),
//      3 bias+leaky, 4 bias+leaky+dot(W3)+b3 -> outd
template <int AMODE, int CFG>
__global__ __launch_bounds__(256) void gemm_mfma(
    const ushort_t* __restrict__ Ah, const ushort_t* __restrict__ Al,
    const float* __restrict__ Af, const float* __restrict__ hsrc,
    const int* __restrict__ psrc, const int* __restrict__ pdst,
    const int* __restrict__ nsrc, const int* __restrict__ ndst,
    const ushort_t* __restrict__ Bth, const ushort_t* __restrict__ Btl,
    int M, int N, int K, int epi,
    const float* __restrict__ bias,
    const ushort_t* __restrict__ hold_hi, const ushort_t* __restrict__ hold_lo,
    const float* __restrict__ skipv, int relu,
    float* __restrict__ Cf, ushort_t* __restrict__ Chi, ushort_t* __restrict__ Clo,
    int Kout, const float* __restrict__ W3, const float* __restrict__ b3,
    float* __restrict__ outd, _Float16* __restrict__ kwmv, float* __restrict__ qbuf) {
  int tid = threadIdx.x;
  int wave = tid >> 6, lane = tid & 63;
  int l16 = lane & 15, q = lane >> 4;
  int m_base, n_base;
  if (CFG == 0) {
    m_base = blockIdx.x * 128 + (wave >> 1) * 64;
    n_base = blockIdx.y * 128 + (wave & 1) * 64;
  } else {
    m_base = blockIdx.x * 256 + wave * 64;
    n_base = 0;
  }
  int kc_count = K >> 5;

  floatx4 acc[4][4];
#pragma unroll
  for (int i = 0; i < 4; i++)
#pragma unroll
    for (int j = 0; j < 4; j++) acc[i][j] = (floatx4){0.f, 0.f, 0.f, 0.f};

  bool tv[4];
  size_t a_base[4];
  int rowA[4], pa[4], pb[4];
#pragma unroll
  for (int mt = 0; mt < 4; mt++) {
    int tile = (m_base >> 4) + mt;
    tv[mt] = (tile * 16) < M;
    if (AMODE == 0) {
      a_base[mt] = ((size_t)(tv[mt] ? tile : 0) * kc_count << 9) + lane * 8;
    } else if (AMODE == 1) {
      rowA[mt] = min(m_base + mt * 16 + l16, M - 1);
    } else {
      int gr = min(m_base + mt * 16 + l16, M - 1);
      bool pos = gr < N_PAIRS;
      int idx = pos ? gr : gr - N_PAIRS;
      pa[mt] = pos ? psrc[idx] : nsrc[idx];
      pb[mt] = pos ? pdst[idx] : ndst[idx];
    }
  }
  size_t b_base[4];
#pragma unroll
  for (int nt = 0; nt < 4; nt++)
    b_base[nt] = ((size_t)((n_base >> 4) + nt) * kc_count << 9) + lane * 8;

  const short8 zer = {0, 0, 0, 0, 0, 0, 0, 0};
  for (int kc = 0; kc < kc_count; kc++) {
    size_t koff = (size_t)kc << 9;
    int kbase = kc * 32 + q * 8;
    short8 b_h[4], b_l[4];
#pragma unroll
    for (int nt = 0; nt < 4; nt++) {
      b_h[nt] = *(const short8*)(Bth + b_base[nt] + koff);
      b_l[nt] = *(const short8*)(Btl + b_base[nt] + koff);
    }
    short8 a_h[4], a_l[4];
#pragma unroll
    for (int mt = 0; mt < 4; mt++) {
      if (AMODE == 0) {
        if (tv[mt]) {
          a_h[mt] = *(const short8*)(Ah + a_base[mt] + koff);
          a_l[mt] = *(const short8*)(Al + a_base[mt] + koff);
        } else {
          a_h[mt] = zer;
          a_l[mt] = zer;
        }
      } else if (AMODE == 1) {
        const float* p = Af + (size_t)rowA[mt] * K + kbase;
        split8(*(const float4*)p, *(const float4*)(p + 4), a_h[mt], a_l[mt]);
      } else {
        const float* ra = hsrc + (size_t)pa[mt] * K + kbase;
        const float* rb = hsrc + (size_t)pb[mt] * K + kbase;
        float4 a0 = *(const float4*)ra, a1 = *(const float4*)(ra + 4);
        float4 c0 = *(const float4*)rb, c1 = *(const float4*)(rb + 4);
        float4 z0 = make_float4(a0.x * c0.x, a0.y * c0.y, a0.z * c0.z, a0.w * c0.w);
        float4 z1 = make_float4(a1.x * c1.x, a1.y * c1.y, a1.z * c1.z, a1.w * c1.w);
        split8(z0, z1, a_h[mt], a_l[mt]);
      }
    }
#pragma unroll
    for (int mt = 0; mt < 4; mt++)
#pragma unroll
      for (int nt = 0; nt < 4; nt++) {
        acc[mt][nt] = __builtin_amdgcn_mfma_f32_16x16x32_bf16(a_h[mt], b_h[nt], acc[mt][nt], 0, 0, 0);
        acc[mt][nt] = __builtin_amdgcn_mfma_f32_16x16x32_bf16(a_h[mt], b_l[nt], acc[mt][nt], 0, 0, 0);
        acc[mt][nt] = __builtin_amdgcn_mfma_f32_16x16x32_bf16(a_l[mt], b_h[nt], acc[mt][nt], 0, 0, 0);
      }
  }

  if (epi == 4) {
    float b3v = b3[0];
#pragma unroll
    for (int mt = 0; mt < 4; mt++) {
      if (!tv[mt]) continue;
#pragma unroll
      for (int r = 0; r < 4; r++) {
        int row = m_base + mt * 16 + q * 4 + r;
        if (row >= M) continue;
        float partial = 0.f;
#pragma unroll
        for (int nt = 0; nt < 4; nt++) {
          int col = n_base + nt * 16 + l16;
          if (col < N) {
            float v = acc[mt][nt][r] + bias[col];
            v = v > 0.f ? v : 0.2f * v;
            partial += v * W3[col];
          }
        }
        partial += __shfl_xor(partial, 1);
        partial += __shfl_xor(partial, 2);
        partial += __shfl_xor(partial, 4);
        partial += __shfl_xor(partial, 8);
        if (l16 == 0) outd[row] = partial + b3v;
      }
    }
    return;
  }

  float alpha = 1.f, beta = 0.f;
  if (epi == 2) {
    float s = *skipv;
    alpha = 1.f / (1.f + __expf(-s));
    beta = 1.f - alpha;
  }
#pragma unroll
  for (int mt = 0; mt < 4; mt++) {
#pragma unroll
    for (int nt = 0; nt < 4; nt++) {
      int col = n_base + nt * 16 + l16;
      if (col >= N) continue;
      float bv = (epi == 0 || epi == 3) ? bias[col] : 0.f;
#pragma unroll
      for (int r = 0; r < 4; r++) {
        int row = m_base + mt * 16 + q * 4 + r;
        if (row >= M) continue;
        float v = acc[mt][nt][r];
        if (epi == 0) {
          v = fmaxf(v + bv, 0.f);
        } else if (epi == 2) {
          size_t ho = packA(row, col, 128);
          float hv = bf2f(hold_hi[ho]) + bf2f(hold_lo[ho]);
          v = alpha * v + beta * hv;
          if (relu) v = fmaxf(v, 0.f);
        } else if (epi == 3) {
          v += bv;
          v = v > 0.f ? v : 0.2f * v;
        }
        if (epi == 1) {
          // kqv split write: col<128 -> kw fp16; 128..255 -> q fp32; >=256 -> mv fp16
          if (col >= 128 && col < 256) {
            qbuf[(size_t)row * 128 + (col - 128)] = v;
          } else {
            int cc = (col < 128) ? col : (col - 128);  // mv goes to 128..255
            kwmv[(size_t)row * 256 + cc] = (_Float16)v;
          }
        } else {
          if (Cf) Cf[(size_t)row * N + col] = v;
          if (Chi) {
            ushort_t hh = f2bf(v);
            size_t o = packA(row, col, Kout);
            Chi[o] = hh;
            Clo[o] = f2bf(v - bf2f(hh));
          }
        }
      }
    }
  }
}

// ---------------- per-destination online-softmax aggregation, fp16 gather table
__global__ __launch_bounds__(256) void edge_agg_kernel(
    const _Float16* __restrict__ kwmv, const float* __restrict__ qbuf,
    const int* __restrict__ poffs, const int2* __restrict__ eld,
    const int* __restrict__ perm,
    ushort_t* __restrict__ agg_hi, ushort_t* __restrict__ agg_lo, int n) {
  int gw = blockIdx.x * 4 + (threadIdx.x >> 6);
  if (gw >= n) return;
  int node = perm[gw];
  int lane = threadIdx.x & 63;
  int c2 = lane & 31, half = lane >> 5;
  int ch = c2 << 2;
  float4 qv = *(const float4*)&qbuf[(size_t)node * 128 + ch];
  int off_half = half * 128 + ch;  // kw at 0..127, mv at 128..255
  float m = -1e30f, s = 0.f;
  float ax = 0.f, ay = 0.f, az = 0.f, aw = 0.f;
  int j = poffs[node], end = poffs[node + 1];
  for (; j < end; j += 8) {
    int2 e0 = eld[j + 0], e1 = eld[j + 1], e2 = eld[j + 2], e3 = eld[j + 3];
    int2 e4 = eld[j + 4], e5 = eld[j + 5], e6 = eld[j + 6], e7 = eld[j + 7];
    half4v v0 = *(const half4v*)&kwmv[(size_t)max(e0.x, 0) * 256 + off_half];
    half4v v1 = *(const half4v*)&kwmv[(size_t)max(e1.x, 0) * 256 + off_half];
    half4v v2 = *(const half4v*)&kwmv[(size_t)max(e2.x, 0) * 256 + off_half];
    half4v v3 = *(const half4v*)&kwmv[(size_t)max(e3.x, 0) * 256 + off_half];
    half4v v4 = *(const half4v*)&kwmv[(size_t)max(e4.x, 0) * 256 + off_half];
    half4v v5 = *(const half4v*)&kwmv[(size_t)max(e5.x, 0) * 256 + off_half];
    half4v v6 = *(const half4v*)&kwmv[(size_t)max(e6.x, 0) * 256 + off_half];
    half4v v7 = *(const half4v*)&kwmv[(size_t)max(e7.x, 0) * 256 + off_half];
    float4 g0 = make_float4((float)v0[0], (float)v0[1], (float)v0[2], (float)v0[3]);
    float4 g1 = make_float4((float)v1[0], (float)v1[1], (float)v1[2], (float)v1[3]);
    float4 g2 = make_float4((float)v2[0], (float)v2[1], (float)v2[2], (float)v2[3]);
    float4 g3 = make_float4((float)v3[0], (float)v3[1], (float)v3[2], (float)v3[3]);
    float4 g4 = make_float4((float)v4[0], (float)v4[1], (float)v4[2], (float)v4[3]);
    float4 g5 = make_float4((float)v5[0], (float)v5[1], (float)v5[2], (float)v5[3]);
    float4 g6 = make_float4((float)v6[0], (float)v6[1], (float)v6[2], (float)v6[3]);
    float4 g7 = make_float4((float)v7[0], (float)v7[1], (float)v7[2], (float)v7[3]);
    float p0 = g0.x * qv.x + g0.y * qv.y + g0.z * qv.z + g0.w * qv.w;
    float p1 = g1.x * qv.x + g1.y * qv.y + g1.z * qv.z + g1.w * qv.w;
    float p2 = g2.x * qv.x + g2.y * qv.y + g2.z * qv.z + g2.w * qv.w;
    float p3 = g3.x * qv.x + g3.y * qv.y + g3.z * qv.z + g3.w * qv.w;
    float p4 = g4.x * qv.x + g4.y * qv.y + g4.z * qv.z + g4.w * qv.w;
    float p5 = g5.x * qv.x + g5.y * qv.y + g5.z * qv.z + g5.w * qv.w;
    float p6 = g6.x * qv.x + g6.y * qv.y + g6.z * qv.z + g6.w * qv.w;
    float p7 = g7.x * qv.x + g7.y * qv.y + g7.z * qv.z + g7.w * qv.w;
    p0 = e0.x >= 0 ? p0 : -1e30f;
    p1 = e1.x >= 0 ? p1 : -1e30f;
    p2 = e2.x >= 0 ? p2 : -1e30f;
    p3 = e3.x >= 0 ? p3 : -1e30f;
    p4 = e4.x >= 0 ? p4 : -1e30f;
    p5 = e5.x >= 0 ? p5 : -1e30f;
    p6 = e6.x >= 0 ? p6 : -1e30f;
    p7 = e7.x >= 0 ? p7 : -1e30f;
    p0 += __shfl_xor(p0, 1); p1 += __shfl_xor(p1, 1);
    p2 += __shfl_xor(p2, 1); p3 += __shfl_xor(p3, 1);
    p4 += __shfl_xor(p4, 1); p5 += __shfl_xor(p5, 1);
    p6 += __shfl_xor(p6, 1); p7 += __shfl_xor(p7, 1);
    p0 += __shfl_xor(p0, 2); p1 += __shfl_xor(p1, 2);
    p2 += __shfl_xor(p2, 2); p3 += __shfl_xor(p3, 2);
    p4 += __shfl_xor(p4, 2); p5 += __shfl_xor(p5, 2);
    p6 += __shfl_xor(p6, 2); p7 += __shfl_xor(p7, 2);
    float o0 = __shfl_xor(p0, 32), o1 = __shfl_xor(p1, 32);
    float o2 = __shfl_xor(p2, 32), o3 = __shfl_xor(p3, 32);
    float o4 = __shfl_xor(p4, 32), o5 = __shfl_xor(p5, 32);
    float o6 = __shfl_xor(p6, 32), o7 = __shfl_xor(p7, 32);
    if (half) { p0 = o0; p1 = o1; p2 = o2; p3 = o3; p4 = o4; p5 = o5; p6 = o6; p7 = o7; }
    float nm = fmaxf(m, fmaxf(fmaxf(fmaxf(p0, p1), fmaxf(p2, p3)),
                              fmaxf(fmaxf(p4, p5), fmaxf(p6, p7))));
    float sc = __expf(m - nm);
    float t0 = __expf(p0 - nm), t1 = __expf(p1 - nm);
    float t2 = __expf(p2 - nm), t3 = __expf(p3 - nm);
    float t4 = __expf(p4 - nm), t5 = __expf(p5 - nm);
    float t6 = __expf(p6 - nm), t7 = __expf(p7 - nm);
    s = s * sc + (((t0 + t1) + (t2 + t3)) + ((t4 + t5) + (t6 + t7)));
    if (half) {
      float w0 = e0.x >= 0 ? __int_as_float(e0.y) : 0.f;
      float w1 = e1.x >= 0 ? __int_as_float(e1.y) : 0.f;
      float w2 = e2.x >= 0 ? __int_as_float(e2.y) : 0.f;
      float w3 = e3.x >= 0 ? __int_as_float(e3.y) : 0.f;
      float w4 = e4.x >= 0 ? __int_as_float(e4.y) : 0.f;
      float w5 = e5.x >= 0 ? __int_as_float(e5.y) : 0.f;
      float w6 = e6.x >= 0 ? __int_as_float(e6.y) : 0.f;
      float w7 = e7.x >= 0 ? __int_as_float(e7.y) : 0.f;
      float f0 = t0 * w0, f1 = t1 * w1, f2 = t2 * w2, f3 = t3 * w3;
      float f4 = t4 * w4, f5 = t5 * w5, f6 = t6 * w6, f7 = t7 * w7;
      ax = ax * sc + ((f0 * g0.x + f1 * g1.x) + (f2 * g2.x + f3 * g3.x)) +
           ((f4 * g4.x + f5 * g5.x) + (f6 * g6.x + f7 * g7.x));
      ay = ay * sc + ((f0 * g0.y + f1 * g1.y) + (f2 * g2.y + f3 * g3.y)) +
           ((f4 * g4.y + f5 * g5.y) + (f6 * g6.y + f7 * g7.y));
      az = az * sc + ((f0 * g0.z + f1 * g1.z) + (f2 * g2.z + f3 * g3.z)) +
           ((f4 * g4.z + f5 * g5.z) + (f6 * g6.z + f7 * g7.z));
      aw = aw * sc + ((f0 * g0.w + f1 * g1.w) + (f2 * g2.w + f3 * g3.w)) +
           ((f4 * g4.w + f5 * g5.w) + (f6 * g6.w + f7 * g7.w));
    }
    m = nm;
  }
  if (half) {
    float inv = (s > 0.f) ? 1.f / s : 0.f;
    float v0 = ax * inv, v1 = ay * inv, v2 = az * inv, v3 = aw * inv;
    ushort_t h0 = f2bf(v0), h1 = f2bf(v1), h2 = f2bf(v2), h3 = f2bf(v3);
    size_t base = packA(node, ch, 128);
    *(uint2*)(agg_hi + base) = make_uint2((unsigned)h0 | ((unsigned)h1 << 16),
                                          (unsigned)h2 | ((unsigned)h3 << 16));
    ushort_t l0 = f2bf(v0 - bf2f(h0)), l1 = f2bf(v1 - bf2f(h1));
    ushort_t l2 = f2bf(v2 - bf2f(h2)), l3 = f2bf(v3 - bf2f(h3));
    *(uint2*)(agg_lo + base) = make_uint2((unsigned)l0 | ((unsigned)l1 << 16),
                                          (unsigned)l2 | ((unsigned)l3 << 16));
  }
}

extern "C" void kernel_launch(void* const* d_in, const int* in_sizes, int n_in,
                              void* d_out, int out_size, void* d_ws, size_t ws_size,
                              hipStream_t stream) {
  const float* x        = (const float*)d_in[0];
  const int*   edge_src = (const int*)d_in[1];
  const int*   edge_dst = (const int*)d_in[2];
  const float* edge_w   = (const float*)d_in[3];
  const int*   pos_src  = (const int*)d_in[4];
  const int*   pos_dst  = (const int*)d_in[5];
  const int*   neg_src  = (const int*)d_in[6];
  const int*   neg_dst  = (const int*)d_in[7];
  const float* W_in     = (const float*)d_in[8];
  const float* b_in     = (const float*)d_in[9];
  const float* Wk       = (const float*)d_in[10];
  const float* Wq       = (const float*)d_in[11];
  const float* Wv       = (const float*)d_in[12];
  const float* att_w    = (const float*)d_in[13];
  const float* msg_w    = (const float*)d_in[14];
  const float* pri      = (const float*)d_in[15];
  const float* Wa       = (const float*)d_in[16];
  const float* skip     = (const float*)d_in[17];
  const float* W1       = (const float*)d_in[18];
  const float* b1       = (const float*)d_in[19];
  const float* W2       = (const float*)d_in[20];
  const float* b2       = (const float*)d_in[21];
  const float* W3       = (const float*)d_in[22];
  const float* b3       = (const float*)d_in[23];
  float* out = (float*)d_out;

  // ---- workspace layout (bytes), ~114 MB
  char* W = (char*)d_ws;
  float*     qbuf   = (float*)(W + 0);             // 25,600,000
  _Float16*  kwmv   = (_Float16*)(W + 25600000);   // 25,600,000
  ushort_t*  h_hi   = (ushort_t*)(W + 51200000);   // 12,800,000
  ushort_t*  h_lo   = (ushort_t*)(W + 64000000);   // 12,800,000
  ushort_t*  agg_hi = (ushort_t*)(W + 76800000);   // 12,800,000
  ushort_t*  agg_lo = (ushort_t*)(W + 89600000);   // 12,800,000
  ushort_t*  Wint_h = (ushort_t*)(W + 102400000);  // 32,768
  ushort_t*  Wint_l = (ushort_t*)(W + 102432768);  // 32,768
  ushort_t*  Wcat_h = (ushort_t*)(W + 102465536);  // 294,912
  ushort_t*  Wcat_l = (ushort_t*)(W + 102760448);  // 294,912
  ushort_t*  Wa_h   = (ushort_t*)(W + 103055360);  // 98,304
  ushort_t*  Wa_l   = (ushort_t*)(W + 103153664);  // 98,304
  ushort_t*  W1_h   = (ushort_t*)(W + 103251968);  // 16,384
  ushort_t*  W1_l   = (ushort_t*)(W + 103268352);  // 16,384
  ushort_t*  W2_h   = (ushort_t*)(W + 103284736);  // 8,192
  ushort_t*  W2_l   = (ushort_t*)(W + 103292928);  // 8,192
  int2*      eld    = (int2*)(W + 103301120);      // 9,600,000 (padded edges)
  int*       deg    = (int*)(W + 112901120);       // 200,000
  int*       poffs  = (int*)(W + 113101120);       // 200,016
  int*       cursor = (int*)(W + 113301136);       // 200,000
  int*       perm   = (int*)(W + 113501136);       // 200,000
  int*       bsum   = (int*)(W + 113701136);       // 1,024
  int*       boff   = (int*)(W + 113702160);       // 1,024
  int*       bh     = (int*)(W + 113703184);       // 1,024
  int*       bcur   = (int*)(W + 113704208);       // 1,024
  // aliases (qbuf/kwmv dead by predictor time)
  ushort_t* T1_h = (ushort_t*)(W + 0);             // 25,600,000
  ushort_t* T1_l = (ushort_t*)(W + 25600000);      // 25,600,000
  float* hfinal = out + 2 * N_PAIRS;

  hipMemsetAsync(deg, 0, N_NODES * sizeof(int), stream);
  hipMemsetAsync(bh, 0, 1024, stream);
  hipMemsetAsync(eld, 0xFF, 9600000, stream);  // sentinel: src=-1

  wprep_kernel<<<880, 256, 0, stream>>>(W_in, Wk, Wq, Wv, att_w, msg_w, pri, Wa, W1, W2,
                                        Wint_h, Wint_l, Wcat_h, Wcat_l, Wa_h, Wa_l,
                                        W1_h, W1_l, W2_h, W2_l);
  hist_kernel<<<(N_EDGES + 255) / 256, 256, 0, stream>>>(edge_dst, deg, N_EDGES);
  scanA_kernel<<<196, 256, 0, stream>>>(deg, poffs, bsum, N_NODES);
  scanB_kernel<<<1, 256, 0, stream>>>(bsum, boff, poffs, 196, N_NODES);
  scanC_kernel<<<196, 256, 0, stream>>>(poffs, boff, cursor, N_NODES);
  scatter_kernel<<<(N_EDGES + 255) / 256, 256, 0, stream>>>(
      edge_src, edge_dst, edge_w, cursor, eld, N_EDGES);
  bhist_kernel<<<196, 256, 0, stream>>>(deg, bh, N_NODES);
  bscan_kernel<<<1, 256, 0, stream>>>(bh, bcur);
  bscatter_kernel<<<196, 256, 0, stream>>>(deg, bcur, perm, N_NODES);

  // input projection: h = relu(x @ W_in + b_in) -> packed hi/lo
  gemm_mfma<1, 0><<<dim3(391, 1), 256, 0, stream>>>(
      nullptr, nullptr, x, nullptr, nullptr, nullptr, nullptr, nullptr,
      Wint_h, Wint_l, N_NODES, 128, 128, 0, b_in, nullptr, nullptr, nullptr, 0,
      nullptr, h_hi, h_lo, 128, nullptr, nullptr, nullptr, nullptr, nullptr);

  for (int l = 0; l < 3; l++) {
    gemm_mfma<0, 0><<<dim3(391, 3), 256, 0, stream>>>(
        h_hi, h_lo, nullptr, nullptr, nullptr, nullptr, nullptr, nullptr,
        Wcat_h + l * 49152, Wcat_l + l * 49152, N_NODES, 384, 128, 1,
        nullptr, nullptr, nullptr, nullptr, 0, nullptr, nullptr, nullptr, 0,
        nullptr, nullptr, nullptr, kwmv, qbuf);
    edge_agg_kernel<<<(N_NODES + 3) / 4, 256, 0, stream>>>(
        kwmv, qbuf, poffs, eld, perm, agg_hi, agg_lo, N_NODES);
    int last = (l == 2);
    gemm_mfma<0, 0><<<dim3(391, 1), 256, 0, stream>>>(
        agg_hi, agg_lo, nullptr, nullptr, nullptr, nullptr, nullptr, nullptr,
        Wa_h + l * 16384, Wa_l + l * 16384, N_NODES, 128, 128, 2,
        nullptr, h_hi, h_lo, skip + l, last ? 0 : 1,
        last ? hfinal : nullptr, last ? nullptr : h_hi, last ? nullptr : h_lo, 128,
        nullptr, nullptr, nullptr, nullptr, nullptr);
  }

  // predictor: one 200000-row pass (pos | neg), zbuild fused into gemm1, dot fused into gemm2
  gemm_mfma<2, 1><<<dim3(782, 1), 256, 0, stream>>>(
      nullptr, nullptr, nullptr, hfinal, pos_src, pos_dst, neg_src, neg_dst,
      W1_h, W1_l, 2 * N_PAIRS, 64, 128, 3, b1, nullptr, nullptr, nullptr, 0,
      nullptr, T1_h, T1_l, 64, nullptr, nullptr, nullptr, nullptr, nullptr);
  gemm_mfma<0, 1><<<dim3(782, 1), 256, 0, stream>>>(
      T1_h, T1_l, nullptr, nullptr, nullptr, nullptr, nullptr, nullptr,
      W2_h, W2_l, 2 * N_PAIRS, 32, 64, 4, b2, nullptr, nullptr, nullptr, 0,
      nullptr, nullptr, nullptr, 0, W3, b3, out, nullptr, nullptr);
}

// Round 6
// 684.961 us; speedup vs baseline: 1.8772x; 1.2795x over previous
//
#include <hip/hip_runtime.h>
#include <cstddef>

#define N_NODES 50000
#define N_EDGES 800000
#define N_PAIRS 100000

typedef short short8 __attribute__((ext_vector_type(8)));
typedef float floatx4 __attribute__((ext_vector_type(4)));
typedef _Float16 half2v __attribute__((ext_vector_type(2)));
typedef _Float16 half4v __attribute__((ext_vector_type(4)));
typedef _Float16 half8v __attribute__((ext_vector_type(8)));
typedef unsigned short ushort_t;

__device__ inline ushort_t f2bf(float x) {
  unsigned u = __float_as_uint(x);
  u += 0x7FFF + ((u >> 16) & 1);  // RNE
  return (ushort_t)(u >> 16);
}
__device__ inline float bf2f(ushort_t h) {
  return __uint_as_float(((unsigned)h) << 16);
}
// packed MFMA A/B-fragment layout: [tile16][kchunk32][lane][8]
__device__ inline size_t packA(int m, int k, int K) {
  return ((size_t)((m >> 4) * (K >> 5) + (k >> 5)) << 9) +
         ((((unsigned)k >> 3) & 3) << 7) + ((m & 15) << 3) + (k & 7);
}
__device__ inline void split8(float4 u0, float4 u1, short8& hi, short8& lo) {
  float f[8] = {u0.x, u0.y, u0.z, u0.w, u1.x, u1.y, u1.z, u1.w};
#pragma unroll
  for (int i = 0; i < 8; i++) {
    ushort_t hh = f2bf(f[i]);
    hi[i] = (short)hh;
    lo[i] = (short)f2bf(f[i] - bf2f(hh));
  }
}
__device__ inline void store_packed8(ushort_t* __restrict__ Chi, ushort_t* __restrict__ Clo,
                                     size_t base, const float* vals) {
  union { ushort_t u[8]; uint4 v; } hi, lo;
#pragma unroll
  for (int i = 0; i < 8; i++) {
    hi.u[i] = f2bf(vals[i]);
    lo.u[i] = f2bf(vals[i] - bf2f(hi.u[i]));
  }
  *(uint4*)(Chi + base) = hi.v;
  *(uint4*)(Clo + base) = lo.v;
}

// ---------------- all-in-one weight prep (fold + transpose + split + pack)
__device__ inline float fold_val(int l, int r, int j, const float* Wk, const float* Wq,
                                 const float* Wv, const float* att, const float* msg,
                                 const float* pri) {
  if (j >= 128 && j < 256) return Wq[(l * 128 + r) * 128 + (j - 128)];
  int jj = j & 127, hh = jj >> 4, e = jj & 15;
  const float* W = (j < 128) ? Wk : Wv;
  const float* T = (j < 128) ? att : msg;
  float s = 0.f;
#pragma unroll
  for (int d = 0; d < 16; d++)
    s += W[(l * 128 + r) * 128 + hh * 16 + d] * T[((l * 8 + hh) * 16 + d) * 16 + e];
  if (j < 128) s *= pri[l * 8 + hh] * 0.25f;
  return s;
}

__global__ void wprep_kernel(const float* __restrict__ W_in, const float* __restrict__ Wk,
                             const float* __restrict__ Wq, const float* __restrict__ Wv,
                             const float* __restrict__ att, const float* __restrict__ msg,
                             const float* __restrict__ pri, const float* __restrict__ Wa,
                             const float* __restrict__ W1, const float* __restrict__ W2,
                             ushort_t* Wint_h, ushort_t* Wint_l,
                             ushort_t* Wcat_h, ushort_t* Wcat_l,
                             ushort_t* Wa_h, ushort_t* Wa_l,
                             ushort_t* W1_h, ushort_t* W1_l,
                             ushort_t* W2_h, ushort_t* W2_l) {
  int gid = blockIdx.x * 256 + threadIdx.x;
  float v;
  ushort_t *dh, *dl;
  size_t o;
  if (gid < 16384) {
    int n = gid >> 7, k = gid & 127;
    v = W_in[k * 128 + n];
    dh = Wint_h; dl = Wint_l; o = packA(n, k, 128);
  } else if (gid < 163840) {
    int t = gid - 16384;
    int l = t / 49152, u = t - l * 49152;
    int n = u >> 7, k = u & 127;
    v = fold_val(l, k, n, Wk, Wq, Wv, att, msg, pri);
    dh = Wcat_h + (size_t)l * 49152; dl = Wcat_l + (size_t)l * 49152;
    o = packA(n, k, 128);
  } else if (gid < 212992) {
    int t = gid - 163840;
    int l = t / 16384, u = t & 16383;
    int n = u >> 7, k = u & 127;
    v = Wa[(size_t)l * 16384 + k * 128 + n];
    dh = Wa_h + (size_t)l * 16384; dl = Wa_l + (size_t)l * 16384;
    o = packA(n, k, 128);
  } else if (gid < 221184) {
    int u = gid - 212992;
    int n = u >> 7, k = u & 127;
    v = W1[k * 64 + n];
    dh = W1_h; dl = W1_l; o = packA(n, k, 128);
  } else if (gid < 225280) {
    int u = gid - 221184;
    int n = u >> 6, k = u & 63;
    v = (n < 32) ? W2[k * 32 + n] : 0.f;
    dh = W2_h; dl = W2_l; o = packA(n, k, 64);
  } else {
    return;
  }
  ushort_t hh = f2bf(v);
  dh[o] = hh;
  dl[o] = f2bf(v - bf2f(hh));
}

// ---------------- CSR build (padded to multiple of 16 per node)
__global__ void hist_kernel(const int* __restrict__ dst, int* __restrict__ deg, int E) {
  int g = blockIdx.x * blockDim.x + threadIdx.x;
  if (g < E) atomicAdd(&deg[dst[g]], 1);
}

__global__ void scanA_kernel(const int* __restrict__ deg, int* __restrict__ offs,
                             int* __restrict__ bsum, int n) {
  __shared__ int sm[256];
  int t = threadIdx.x;
  int i = blockIdx.x * 256 + t;
  int v = (i < n) ? ((deg[i] + 15) & ~15) : 0;
  sm[t] = v;
  __syncthreads();
  for (int off = 1; off < 256; off <<= 1) {
    int u = (t >= off) ? sm[t - off] : 0;
    __syncthreads();
    sm[t] += u;
    __syncthreads();
  }
  if (i < n) offs[i] = sm[t] - v;
  if (t == 255) bsum[blockIdx.x] = sm[255];
}

__global__ void scanB_kernel(const int* __restrict__ bsum, int* __restrict__ boff,
                             int* __restrict__ offs, int nb, int n) {
  __shared__ int sm[256];
  int t = threadIdx.x;
  int v = (t < nb) ? bsum[t] : 0;
  sm[t] = v;
  __syncthreads();
  for (int off = 1; off < 256; off <<= 1) {
    int u = (t >= off) ? sm[t - off] : 0;
    __syncthreads();
    sm[t] += u;
    __syncthreads();
  }
  boff[t] = sm[t] - v;
  if (t == nb - 1) offs[n] = sm[t];
}

__global__ void scanC_kernel(int* __restrict__ offs, const int* __restrict__ boff,
                             int* __restrict__ cursor, int n) {
  int i = blockIdx.x * 256 + threadIdx.x;
  if (i < n) {
    int o = offs[i] + boff[blockIdx.x];
    offs[i] = o;
    cursor[i] = o;
  }
}

__global__ void scatter_kernel(const int* __restrict__ src, const int* __restrict__ dst,
                               const float* __restrict__ w, int* __restrict__ cursor,
                               int2* __restrict__ eld, int E) {
  int g = blockIdx.x * blockDim.x + threadIdx.x;
  if (g < E) {
    int d = dst[g];
    int p = atomicAdd(&cursor[d], 1);
    eld[p] = make_int2(src[g], __float_as_int(w[g]));
  }
}

// ---------------- degree-descending node permutation (counting sort, 256 buckets)
__global__ void bhist_kernel(const int* __restrict__ deg, int* __restrict__ bh, int n) {
  __shared__ int lh[256];
  int t = threadIdx.x;
  lh[t] = 0;
  __syncthreads();
  int i = blockIdx.x * 256 + t;
  if (i < n) atomicAdd(&lh[min(deg[i], 255)], 1);
  __syncthreads();
  if (lh[t]) atomicAdd(&bh[t], lh[t]);
}
__global__ void bscan_kernel(const int* __restrict__ bh, int* __restrict__ bcur) {
  __shared__ int sm[256];
  int t = threadIdx.x;
  int v = bh[255 - t];
  sm[t] = v;
  __syncthreads();
  for (int off = 1; off < 256; off <<= 1) {
    int u = (t >= off) ? sm[t - off] : 0;
    __syncthreads();
    sm[t] += u;
    __syncthreads();
  }
  bcur[255 - t] = sm[t] - v;
}
__global__ void bscatter_kernel(const int* __restrict__ deg, int* __restrict__ bcur,
                                int* __restrict__ perm, int n) {
  __shared__ int lh[256], lbase[256];
  int t = threadIdx.x;
  lh[t] = 0;
  __syncthreads();
  int i = blockIdx.x * 256 + t;
  int b = 0, local = 0;
  if (i < n) {
    b = min(deg[i], 255);
    local = atomicAdd(&lh[b], 1);
  }
  __syncthreads();
  int cnt = lh[t];
  lbase[t] = cnt ? atomicAdd(&bcur[t], cnt) : 0;
  __syncthreads();
  if (i < n) perm[lbase[b] + local] = i;
}

// ---------------- split-bf16 MFMA GEMM with LDS-transpose vectorized epilogue
// AMODE: 0 packed hi/lo A; 1 fp32 row-major A (split on fly); 2 pair-product gather
// CFG: 0 = 2x2 waves (128x128); 1 = 4x1 waves (256m x 64n)
// epi: 0 bias+relu->packed, 1 kqv write (kw/mv fp16, q fp16), 2 skip-mix(+relu),
//      3 bias+leaky->packed, 4 bias+leaky+dot(W3)+b3 -> outd
template <int AMODE, int CFG>
__global__ __launch_bounds__(256) void gemm_mfma(
    const ushort_t* __restrict__ Ah, const ushort_t* __restrict__ Al,
    const float* __restrict__ Af, const float* __restrict__ hsrc,
    const int* __restrict__ psrc, const int* __restrict__ pdst,
    const int* __restrict__ nsrc, const int* __restrict__ ndst,
    const ushort_t* __restrict__ Bth, const ushort_t* __restrict__ Btl,
    int M, int N, int K, int epi,
    const float* __restrict__ bias,
    const ushort_t* __restrict__ hold_hi, const ushort_t* __restrict__ hold_lo,
    const float* __restrict__ skipv, int relu,
    float* __restrict__ Cf, ushort_t* __restrict__ Chi, ushort_t* __restrict__ Clo,
    int Kout, const float* __restrict__ W3, const float* __restrict__ b3,
    float* __restrict__ outd, _Float16* __restrict__ kwmv, _Float16* __restrict__ qbuf) {
  int tid = threadIdx.x;
  int wave = tid >> 6, lane = tid & 63;
  int l16 = lane & 15, q = lane >> 4;
  int m_base, n_base;
  if (CFG == 0) {
    m_base = blockIdx.x * 128 + (wave >> 1) * 64;
    n_base = blockIdx.y * 128 + (wave & 1) * 64;
  } else {
    m_base = blockIdx.x * 256 + wave * 64;
    n_base = 0;
  }
  int kc_count = K >> 5;

  floatx4 acc[4][4];
#pragma unroll
  for (int i = 0; i < 4; i++)
#pragma unroll
    for (int j = 0; j < 4; j++) acc[i][j] = (floatx4){0.f, 0.f, 0.f, 0.f};

  bool tv[4];
  size_t a_base[4];
  int rowA[4], pa[4], pb[4];
#pragma unroll
  for (int mt = 0; mt < 4; mt++) {
    int tile = (m_base >> 4) + mt;
    tv[mt] = (tile * 16) < M;
    if (AMODE == 0) {
      a_base[mt] = ((size_t)(tv[mt] ? tile : 0) * kc_count << 9) + lane * 8;
    } else if (AMODE == 1) {
      rowA[mt] = min(m_base + mt * 16 + l16, M - 1);
    } else {
      int gr = min(m_base + mt * 16 + l16, M - 1);
      bool pos = gr < N_PAIRS;
      int idx = pos ? gr : gr - N_PAIRS;
      pa[mt] = pos ? psrc[idx] : nsrc[idx];
      pb[mt] = pos ? pdst[idx] : ndst[idx];
    }
  }
  size_t b_base[4];
#pragma unroll
  for (int nt = 0; nt < 4; nt++)
    b_base[nt] = ((size_t)((n_base >> 4) + nt) * kc_count << 9) + lane * 8;

  const short8 zer = {0, 0, 0, 0, 0, 0, 0, 0};
  for (int kc = 0; kc < kc_count; kc++) {
    size_t koff = (size_t)kc << 9;
    int kbase = kc * 32 + q * 8;
    short8 b_h[4], b_l[4];
#pragma unroll
    for (int nt = 0; nt < 4; nt++) {
      b_h[nt] = *(const short8*)(Bth + b_base[nt] + koff);
      b_l[nt] = *(const short8*)(Btl + b_base[nt] + koff);
    }
    short8 a_h[4], a_l[4];
#pragma unroll
    for (int mt = 0; mt < 4; mt++) {
      if (AMODE == 0) {
        if (tv[mt]) {
          a_h[mt] = *(const short8*)(Ah + a_base[mt] + koff);
          a_l[mt] = *(const short8*)(Al + a_base[mt] + koff);
        } else {
          a_h[mt] = zer;
          a_l[mt] = zer;
        }
      } else if (AMODE == 1) {
        const float* p = Af + (size_t)rowA[mt] * K + kbase;
        split8(*(const float4*)p, *(const float4*)(p + 4), a_h[mt], a_l[mt]);
      } else {
        const float* ra = hsrc + (size_t)pa[mt] * K + kbase;
        const float* rb = hsrc + (size_t)pb[mt] * K + kbase;
        float4 a0 = *(const float4*)ra, a1 = *(const float4*)(ra + 4);
        float4 c0 = *(const float4*)rb, c1 = *(const float4*)(rb + 4);
        float4 z0 = make_float4(a0.x * c0.x, a0.y * c0.y, a0.z * c0.z, a0.w * c0.w);
        float4 z1 = make_float4(a1.x * c1.x, a1.y * c1.y, a1.z * c1.z, a1.w * c1.w);
        split8(z0, z1, a_h[mt], a_l[mt]);
      }
    }
#pragma unroll
    for (int mt = 0; mt < 4; mt++)
#pragma unroll
      for (int nt = 0; nt < 4; nt++) {
        acc[mt][nt] = __builtin_amdgcn_mfma_f32_16x16x32_bf16(a_h[mt], b_h[nt], acc[mt][nt], 0, 0, 0);
        acc[mt][nt] = __builtin_amdgcn_mfma_f32_16x16x32_bf16(a_h[mt], b_l[nt], acc[mt][nt], 0, 0, 0);
        acc[mt][nt] = __builtin_amdgcn_mfma_f32_16x16x32_bf16(a_l[mt], b_h[nt], acc[mt][nt], 0, 0, 0);
      }
  }

  // ---- LDS-transpose epilogue: lane ends up with 8 consecutive cols of one row
  __shared__ float ldsT[4][16 * 68];
  float* myT = &ldsT[wave][0];
  float alpha = 1.f, beta = 0.f;
  if (epi == 2) {
    float sv = *skipv;
    alpha = 1.f / (1.f + __expf(-sv));
    beta = 1.f - alpha;
  }
  float b3v = (epi == 4) ? b3[0] : 0.f;
  int g = lane >> 4, mloc = lane & 15;
#pragma unroll
  for (int mt = 0; mt < 4; mt++) {
    int row0 = m_base + mt * 16;
#pragma unroll
    for (int nt = 0; nt < 4; nt++)
#pragma unroll
      for (int r = 0; r < 4; r++)
        myT[(q * 4 + r) * 68 + nt * 16 + l16] = acc[mt][nt][r];
    __syncthreads();
    if (tv[mt]) {
      int row = row0 + mloc;
      float outacc = 0.f;
#pragma unroll
      for (int kc2 = 0; kc2 < 2; kc2++) {
        const float* rp = myT + mloc * 68 + kc2 * 32 + g * 8;
        floatx4 v0 = *(const floatx4*)rp;
        floatx4 v1 = *(const floatx4*)(rp + 4);
        float vals[8] = {v0[0], v0[1], v0[2], v0[3], v1[0], v1[1], v1[2], v1[3]};
        int col0 = n_base + kc2 * 32 + g * 8;
        size_t pbase = ((size_t)((row0 >> 4) * (Kout >> 5) + ((n_base >> 5) + kc2)) << 9) +
                       (size_t)lane * 8;
        if (epi == 0) {
          float4 bb0 = *(const float4*)&bias[col0];
          float4 bb1 = *(const float4*)&bias[col0 + 4];
          float bb[8] = {bb0.x, bb0.y, bb0.z, bb0.w, bb1.x, bb1.y, bb1.z, bb1.w};
#pragma unroll
          for (int j = 0; j < 8; j++) vals[j] = fmaxf(vals[j] + bb[j], 0.f);
          store_packed8(Chi, Clo, pbase, vals);
        } else if (epi == 1) {
          int region = n_base >> 7;  // 0 kw, 1 q, 2 mv
          half8v hv;
#pragma unroll
          for (int j = 0; j < 8; j++) hv[j] = (_Float16)vals[j];
          if (region == 1) {
            *(half8v*)&qbuf[(size_t)row * 128 + (col0 - 128)] = hv;
          } else {
            int cc = (region == 0) ? col0 : (col0 - 128);  // mv cols 256.. -> 128..
            *(half8v*)&kwmv[(size_t)row * 256 + cc] = hv;
          }
        } else if (epi == 2) {
          uint4 hhv = *(const uint4*)(hold_hi + pbase);
          uint4 hlv = *(const uint4*)(hold_lo + pbase);
          unsigned hu[4] = {hhv.x, hhv.y, hhv.z, hhv.w};
          unsigned lu[4] = {hlv.x, hlv.y, hlv.z, hlv.w};
#pragma unroll
          for (int j = 0; j < 8; j++) {
            ushort_t hh = (ushort_t)(hu[j >> 1] >> ((j & 1) * 16));
            ushort_t hl = (ushort_t)(lu[j >> 1] >> ((j & 1) * 16));
            float hvf = bf2f(hh) + bf2f(hl);
            vals[j] = alpha * vals[j] + beta * hvf;
            if (relu) vals[j] = fmaxf(vals[j], 0.f);
          }
          if (Cf) {
            *(float4*)&Cf[(size_t)row * N + col0] =
                make_float4(vals[0], vals[1], vals[2], vals[3]);
            *(float4*)&Cf[(size_t)row * N + col0 + 4] =
                make_float4(vals[4], vals[5], vals[6], vals[7]);
          }
          if (Chi) store_packed8(Chi, Clo, pbase, vals);
        } else if (epi == 3) {
          float4 bb0 = *(const float4*)&bias[col0];
          float4 bb1 = *(const float4*)&bias[col0 + 4];
          float bb[8] = {bb0.x, bb0.y, bb0.z, bb0.w, bb1.x, bb1.y, bb1.z, bb1.w};
#pragma unroll
          for (int j = 0; j < 8; j++) {
            float v = vals[j] + bb[j];
            vals[j] = v > 0.f ? v : 0.2f * v;
          }
          store_packed8(Chi, Clo, pbase, vals);
        } else {  // epi 4
          bool inb = col0 < N;
          float4 bb0 = inb ? *(const float4*)&bias[col0] : make_float4(0, 0, 0, 0);
          float4 bb1 = inb ? *(const float4*)&bias[col0 + 4] : make_float4(0, 0, 0, 0);
          float4 w0 = inb ? *(const float4*)&W3[col0] : make_float4(0, 0, 0, 0);
          float4 w1 = inb ? *(const float4*)&W3[col0 + 4] : make_float4(0, 0, 0, 0);
          float bb[8] = {bb0.x, bb0.y, bb0.z, bb0.w, bb1.x, bb1.y, bb1.z, bb1.w};
          float ww[8] = {w0.x, w0.y, w0.z, w0.w, w1.x, w1.y, w1.z, w1.w};
#pragma unroll
          for (int j = 0; j < 8; j++) {
            float v = vals[j] + bb[j];
            v = v > 0.f ? v : 0.2f * v;
            outacc += v * ww[j];
          }
        }
      }
      if (epi == 4) {
        outacc += __shfl_xor(outacc, 16);
        outacc += __shfl_xor(outacc, 32);
        if (lane < 16) outd[row0 + lane] = outacc + b3v;
      }
    }
    __syncthreads();
  }
}

// ---------------- per-destination online-softmax aggregation
// half-wave = edge parity; lane covers 4 channels of all 128; fdot2 logits
__global__ __launch_bounds__(256) void edge_agg_kernel(
    const _Float16* __restrict__ kwmv, const _Float16* __restrict__ qbuf,
    const int* __restrict__ poffs, const int2* __restrict__ eld,
    const int* __restrict__ perm,
    ushort_t* __restrict__ agg_hi, ushort_t* __restrict__ agg_lo, int n) {
  int wslot = blockIdx.x * 4 + (threadIdx.x >> 6);
  int lane = threadIdx.x & 63;
  int hh = lane >> 5;
  int c4 = lane & 31;
  int ch = c4 << 2;
  for (int gw = wslot; gw < n; gw += 8192) {
    int node = perm[gw];
    half4v qv = *(const half4v*)&qbuf[(size_t)node * 128 + ch];
    half2v q01 = {qv[0], qv[1]}, q23 = {qv[2], qv[3]};
    float m = -1e30f, s = 0.f;
    float a0 = 0.f, a1 = 0.f, a2 = 0.f, a3 = 0.f;
    int beg = poffs[node], end = poffs[node + 1];
    for (int j = beg; j < end; j += 16) {
      int2 e[8];
      half4v kv[8], mv[8];
#pragma unroll
      for (int i = 0; i < 8; i++) {
        e[i] = eld[j + 2 * i + hh];
        size_t srow = (size_t)max(e[i].x, 0) * 256;
        kv[i] = *(const half4v*)&kwmv[srow + ch];
        mv[i] = *(const half4v*)&kwmv[srow + 128 + ch];
      }
      float p[8];
#pragma unroll
      for (int i = 0; i < 8; i++) {
        half2v k01 = {kv[i][0], kv[i][1]}, k23 = {kv[i][2], kv[i][3]};
        float d = __builtin_amdgcn_fdot2(
            k01, q01, __builtin_amdgcn_fdot2(k23, q23, 0.f, false), false);
        d += __shfl_xor(d, 1);
        d += __shfl_xor(d, 2);
        p[i] = (e[i].x >= 0) ? d : -1e30f;
      }
      float nm = m;
#pragma unroll
      for (int i = 0; i < 8; i++) nm = fmaxf(nm, p[i]);
      float sc = __expf(m - nm);
      float t[8];
      float ssum = 0.f;
#pragma unroll
      for (int i = 0; i < 8; i++) {
        t[i] = __expf(p[i] - nm);
        ssum += t[i];
      }
      s = s * sc + ssum;
      a0 *= sc; a1 *= sc; a2 *= sc; a3 *= sc;
#pragma unroll
      for (int i = 0; i < 8; i++) {
        float w = (e[i].x >= 0) ? __int_as_float(e[i].y) : 0.f;
        float f = t[i] * w;
        a0 += f * (float)mv[i][0];
        a1 += f * (float)mv[i][1];
        a2 += f * (float)mv[i][2];
        a3 += f * (float)mv[i][3];
      }
      m = nm;
    }
    // merge halves
    float mo = __shfl_xor(m, 32);
    float so = __shfl_xor(s, 32);
    float c0 = __shfl_xor(a0, 32), c1 = __shfl_xor(a1, 32);
    float c2 = __shfl_xor(a2, 32), c3 = __shfl_xor(a3, 32);
    float M = fmaxf(m, mo);
    float e1 = __expf(m - M), e2 = __expf(mo - M);
    float st = s * e1 + so * e2;
    float v0 = a0 * e1 + c0 * e2, v1 = a1 * e1 + c1 * e2;
    float v2 = a2 * e1 + c2 * e2, v3 = a3 * e1 + c3 * e2;
    float inv = (st > 0.f) ? 1.f / st : 0.f;
    v0 *= inv; v1 *= inv; v2 *= inv; v3 *= inv;
    if (hh == 0) {
      size_t base = packA(node, ch, 128);
      ushort_t h0 = f2bf(v0), h1 = f2bf(v1), h2 = f2bf(v2), h3 = f2bf(v3);
      *(uint2*)(agg_hi + base) =
          make_uint2((unsigned)h0 | ((unsigned)h1 << 16), (unsigned)h2 | ((unsigned)h3 << 16));
      ushort_t l0 = f2bf(v0 - bf2f(h0)), l1 = f2bf(v1 - bf2f(h1));
      ushort_t l2 = f2bf(v2 - bf2f(h2)), l3 = f2bf(v3 - bf2f(h3));
      *(uint2*)(agg_lo + base) =
          make_uint2((unsigned)l0 | ((unsigned)l1 << 16), (unsigned)l2 | ((unsigned)l3 << 16));
    }
  }
}

extern "C" void kernel_launch(void* const* d_in, const int* in_sizes, int n_in,
                              void* d_out, int out_size, void* d_ws, size_t ws_size,
                              hipStream_t stream) {
  const float* x        = (const float*)d_in[0];
  const int*   edge_src = (const int*)d_in[1];
  const int*   edge_dst = (const int*)d_in[2];
  const float* edge_w   = (const float*)d_in[3];
  const int*   pos_src  = (const int*)d_in[4];
  const int*   pos_dst  = (const int*)d_in[5];
  const int*   neg_src  = (const int*)d_in[6];
  const int*   neg_dst  = (const int*)d_in[7];
  const float* W_in     = (const float*)d_in[8];
  const float* b_in     = (const float*)d_in[9];
  const float* Wk       = (const float*)d_in[10];
  const float* Wq       = (const float*)d_in[11];
  const float* Wv       = (const float*)d_in[12];
  const float* att_w    = (const float*)d_in[13];
  const float* msg_w    = (const float*)d_in[14];
  const float* pri      = (const float*)d_in[15];
  const float* Wa       = (const float*)d_in[16];
  const float* skip     = (const float*)d_in[17];
  const float* W1       = (const float*)d_in[18];
  const float* b1       = (const float*)d_in[19];
  const float* W2       = (const float*)d_in[20];
  const float* b2       = (const float*)d_in[21];
  const float* W3       = (const float*)d_in[22];
  const float* b3       = (const float*)d_in[23];
  float* out = (float*)d_out;

  // ---- workspace layout (bytes), ~104 MB
  char* W = (char*)d_ws;
  _Float16*  qbuf   = (_Float16*)(W + 0);          // 12,800,000
  _Float16*  kwmv   = (_Float16*)(W + 12800000);   // 25,600,000
  ushort_t*  h_hi   = (ushort_t*)(W + 38400000);   // 12,800,000
  ushort_t*  h_lo   = (ushort_t*)(W + 51200000);   // 12,800,000
  ushort_t*  agg_hi = (ushort_t*)(W + 64000000);   // 12,800,000
  ushort_t*  agg_lo = (ushort_t*)(W + 76800000);   // 12,800,000
  ushort_t*  Wint_h = (ushort_t*)(W + 89600000);   // 32,768
  ushort_t*  Wint_l = (ushort_t*)(W + 89632768);   // 32,768
  ushort_t*  Wcat_h = (ushort_t*)(W + 89665536);   // 294,912
  ushort_t*  Wcat_l = (ushort_t*)(W + 89960448);   // 294,912
  ushort_t*  Wa_h   = (ushort_t*)(W + 90255360);   // 98,304
  ushort_t*  Wa_l   = (ushort_t*)(W + 90353664);   // 98,304
  ushort_t*  W1_h   = (ushort_t*)(W + 90451968);   // 16,384
  ushort_t*  W1_l   = (ushort_t*)(W + 90468352);   // 16,384
  ushort_t*  W2_h   = (ushort_t*)(W + 90484736);   // 8,192
  ushort_t*  W2_l   = (ushort_t*)(W + 90492928);   // 8,192
  int2*      eld    = (int2*)(W + 90501120);       // 12,800,000 (padded-16 edges)
  int*       deg    = (int*)(W + 103301120);       // 200,000
  int*       poffs  = (int*)(W + 103501120);       // 200,016
  int*       cursor = (int*)(W + 103701136);       // 200,000
  int*       perm   = (int*)(W + 103901136);       // 200,000
  int*       bsum   = (int*)(W + 104101136);       // 1,024
  int*       boff   = (int*)(W + 104102160);       // 1,024
  int*       bh     = (int*)(W + 104103184);       // 1,024
  int*       bcur   = (int*)(W + 104104208);       // 1,024
  // aliases (qbuf/kwmv/h dead by predictor time)
  ushort_t* T1_h = (ushort_t*)(W + 0);             // 25,600,000
  ushort_t* T1_l = (ushort_t*)(W + 25600000);      // 25,600,000
  float* hfinal = out + 2 * N_PAIRS;

  hipMemsetAsync(deg, 0, N_NODES * sizeof(int), stream);
  hipMemsetAsync(bh, 0, 1024, stream);
  hipMemsetAsync(eld, 0xFF, 12800000, stream);  // sentinel: src=-1

  wprep_kernel<<<880, 256, 0, stream>>>(W_in, Wk, Wq, Wv, att_w, msg_w, pri, Wa, W1, W2,
                                        Wint_h, Wint_l, Wcat_h, Wcat_l, Wa_h, Wa_l,
                                        W1_h, W1_l, W2_h, W2_l);
  hist_kernel<<<(N_EDGES + 255) / 256, 256, 0, stream>>>(edge_dst, deg, N_EDGES);
  scanA_kernel<<<196, 256, 0, stream>>>(deg, poffs, bsum, N_NODES);
  scanB_kernel<<<1, 256, 0, stream>>>(bsum, boff, poffs, 196, N_NODES);
  scanC_kernel<<<196, 256, 0, stream>>>(poffs, boff, cursor, N_NODES);
  scatter_kernel<<<(N_EDGES + 255) / 256, 256, 0, stream>>>(
      edge_src, edge_dst, edge_w, cursor, eld, N_EDGES);
  bhist_kernel<<<196, 256, 0, stream>>>(deg, bh, N_NODES);
  bscan_kernel<<<1, 256, 0, stream>>>(bh, bcur);
  bscatter_kernel<<<196, 256, 0, stream>>>(deg, bcur, perm, N_NODES);

  // input projection: h = relu(x @ W_in + b_in) -> packed hi/lo
  gemm_mfma<1, 0><<<dim3(391, 1), 256, 0, stream>>>(
      nullptr, nullptr, x, nullptr, nullptr, nullptr, nullptr, nullptr,
      Wint_h, Wint_l, N_NODES, 128, 128, 0, b_in, nullptr, nullptr, nullptr, 0,
      nullptr, h_hi, h_lo, 128, nullptr, nullptr, nullptr, nullptr, nullptr);

  for (int l = 0; l < 3; l++) {
    gemm_mfma<0, 0><<<dim3(391, 3), 256, 0, stream>>>(
        h_hi, h_lo, nullptr, nullptr, nullptr, nullptr, nullptr, nullptr,
        Wcat_h + l * 49152, Wcat_l + l * 49152, N_NODES, 384, 128, 1,
        nullptr, nullptr, nullptr, nullptr, 0, nullptr, nullptr, nullptr, 128,
        nullptr, nullptr, nullptr, kwmv, qbuf);
    edge_agg_kernel<<<2048, 256, 0, stream>>>(
        kwmv, qbuf, poffs, eld, perm, agg_hi, agg_lo, N_NODES);
    int last = (l == 2);
    gemm_mfma<0, 0><<<dim3(391, 1), 256, 0, stream>>>(
        agg_hi, agg_lo, nullptr, nullptr, nullptr, nullptr, nullptr, nullptr,
        Wa_h + l * 16384, Wa_l + l * 16384, N_NODES, 128, 128, 2,
        nullptr, h_hi, h_lo, skip + l, last ? 0 : 1,
        last ? hfinal : nullptr, last ? nullptr : h_hi, last ? nullptr : h_lo, 128,
        nullptr, nullptr, nullptr, nullptr, nullptr);
  }

  // predictor: one 200000-row pass (pos | neg)
  gemm_mfma<2, 1><<<dim3(782, 1), 256, 0, stream>>>(
      nullptr, nullptr, nullptr, hfinal, pos_src, pos_dst, neg_src, neg_dst,
      W1_h, W1_l, 2 * N_PAIRS, 64, 128, 3, b1, nullptr, nullptr, nullptr, 0,
      nullptr, T1_h, T1_l, 64, nullptr, nullptr, nullptr, nullptr, nullptr);
  gemm_mfma<0, 1><<<dim3(782, 1), 256, 0, stream>>>(
      T1_h, T1_l, nullptr, nullptr, nullptr, nullptr, nullptr, nullptr,
      W2_h, W2_l, 2 * N_PAIRS, 32, 64, 4, b2, nullptr, nullptr, nullptr, 0,
      nullptr, nullptr, nullptr, 64, W3, b3, out, nullptr, nullptr);
}

// Round 7
// 622.212 us; speedup vs baseline: 2.0665x; 1.1008x over previous
//
#include <hip/hip_runtime.h>
#include <cstddef>

#define N_NODES 50000
#define N_EDGES 800000
#define N_PAIRS 100000

typedef float floatx4 __attribute__((ext_vector_type(4)));
typedef _Float16 half2v __attribute__((ext_vector_type(2)));
typedef _Float16 half4v __attribute__((ext_vector_type(4)));
typedef _Float16 half8v __attribute__((ext_vector_type(8)));

// packed MFMA A/B-fragment layout: [tile16][kchunk32][lane][8] (elements = fp16)
__device__ inline size_t packA(int m, int k, int K) {
  return ((size_t)((m >> 4) * (K >> 5) + (k >> 5)) << 9) +
         ((((unsigned)k >> 3) & 3) << 7) + ((m & 15) << 3) + (k & 7);
}
__device__ inline void store_h8(_Float16* __restrict__ dst, size_t base, const float* vals) {
  half8v hv;
#pragma unroll
  for (int i = 0; i < 8; i++) hv[i] = (_Float16)vals[i];
  *(half8v*)(dst + base) = hv;
}

// ---------------- all-in-one weight prep (fold + transpose + pack, fp16)
__device__ inline float fold_val(int l, int r, int j, const float* Wk, const float* Wq,
                                 const float* Wv, const float* att, const float* msg,
                                 const float* pri) {
  if (j >= 128 && j < 256) return Wq[(l * 128 + r) * 128 + (j - 128)];
  int jj = j & 127, hh = jj >> 4, e = jj & 15;
  const float* W = (j < 128) ? Wk : Wv;
  const float* T = (j < 128) ? att : msg;
  float s = 0.f;
#pragma unroll
  for (int d = 0; d < 16; d++)
    s += W[(l * 128 + r) * 128 + hh * 16 + d] * T[((l * 8 + hh) * 16 + d) * 16 + e];
  if (j < 128) s *= pri[l * 8 + hh] * 0.25f;
  return s;
}

__global__ void wprep_kernel(const float* __restrict__ W_in, const float* __restrict__ Wk,
                             const float* __restrict__ Wq, const float* __restrict__ Wv,
                             const float* __restrict__ att, const float* __restrict__ msg,
                             const float* __restrict__ pri, const float* __restrict__ Wa,
                             const float* __restrict__ W1, const float* __restrict__ W2,
                             _Float16* Wint, _Float16* Wcat, _Float16* Waf,
                             _Float16* W1f, _Float16* W2f) {
  int gid = blockIdx.x * 256 + threadIdx.x;
  float v;
  _Float16* dt;
  size_t o;
  if (gid < 16384) {
    int n = gid >> 7, k = gid & 127;
    v = W_in[k * 128 + n];
    dt = Wint; o = packA(n, k, 128);
  } else if (gid < 163840) {
    int t = gid - 16384;
    int l = t / 49152, u = t - l * 49152;
    int n = u >> 7, k = u & 127;
    v = fold_val(l, k, n, Wk, Wq, Wv, att, msg, pri);
    dt = Wcat + (size_t)l * 49152;
    o = packA(n, k, 128);
  } else if (gid < 212992) {
    int t = gid - 163840;
    int l = t / 16384, u = t & 16383;
    int n = u >> 7, k = u & 127;
    v = Wa[(size_t)l * 16384 + k * 128 + n];
    dt = Waf + (size_t)l * 16384;
    o = packA(n, k, 128);
  } else if (gid < 221184) {
    int u = gid - 212992;
    int n = u >> 7, k = u & 127;
    v = W1[k * 64 + n];
    dt = W1f; o = packA(n, k, 128);
  } else if (gid < 225280) {
    int u = gid - 221184;
    int n = u >> 6, k = u & 63;
    v = (n < 32) ? W2[k * 32 + n] : 0.f;
    dt = W2f; o = packA(n, k, 64);
  } else {
    return;
  }
  dt[o] = (_Float16)v;
}

// ---------------- CSR build (padded to multiple of 16 per node)
__global__ void hist_kernel(const int* __restrict__ dst, int* __restrict__ deg, int E) {
  int g = blockIdx.x * blockDim.x + threadIdx.x;
  if (g < E) atomicAdd(&deg[dst[g]], 1);
}

__global__ void scanA_kernel(const int* __restrict__ deg, int* __restrict__ offs,
                             int* __restrict__ bsum, int n) {
  __shared__ int sm[256];
  int t = threadIdx.x;
  int i = blockIdx.x * 256 + t;
  int v = (i < n) ? ((deg[i] + 15) & ~15) : 0;
  sm[t] = v;
  __syncthreads();
  for (int off = 1; off < 256; off <<= 1) {
    int u = (t >= off) ? sm[t - off] : 0;
    __syncthreads();
    sm[t] += u;
    __syncthreads();
  }
  if (i < n) offs[i] = sm[t] - v;
  if (t == 255) bsum[blockIdx.x] = sm[255];
}

__global__ void scanB_kernel(const int* __restrict__ bsum, int* __restrict__ boff,
                             int* __restrict__ offs, int nb, int n) {
  __shared__ int sm[256];
  int t = threadIdx.x;
  int v = (t < nb) ? bsum[t] : 0;
  sm[t] = v;
  __syncthreads();
  for (int off = 1; off < 256; off <<= 1) {
    int u = (t >= off) ? sm[t - off] : 0;
    __syncthreads();
    sm[t] += u;
    __syncthreads();
  }
  boff[t] = sm[t] - v;
  if (t == nb - 1) offs[n] = sm[t];
}

__global__ void scanC_kernel(int* __restrict__ offs, const int* __restrict__ boff,
                             int* __restrict__ cursor, int n) {
  int i = blockIdx.x * 256 + threadIdx.x;
  if (i < n) {
    int o = offs[i] + boff[blockIdx.x];
    offs[i] = o;
    cursor[i] = o;
  }
}

__global__ void scatter_kernel(const int* __restrict__ src, const int* __restrict__ dst,
                               const float* __restrict__ w, int* __restrict__ cursor,
                               int2* __restrict__ eld, int E) {
  int g = blockIdx.x * blockDim.x + threadIdx.x;
  if (g < E) {
    int d = dst[g];
    int p = atomicAdd(&cursor[d], 1);
    eld[p] = make_int2(src[g], __float_as_int(w[g]));
  }
}

// ---------------- degree-descending node permutation (counting sort, 256 buckets)
__global__ void bhist_kernel(const int* __restrict__ deg, int* __restrict__ bh, int n) {
  __shared__ int lh[256];
  int t = threadIdx.x;
  lh[t] = 0;
  __syncthreads();
  int i = blockIdx.x * 256 + t;
  if (i < n) atomicAdd(&lh[min(deg[i], 255)], 1);
  __syncthreads();
  if (lh[t]) atomicAdd(&bh[t], lh[t]);
}
__global__ void bscan_kernel(const int* __restrict__ bh, int* __restrict__ bcur) {
  __shared__ int sm[256];
  int t = threadIdx.x;
  int v = bh[255 - t];
  sm[t] = v;
  __syncthreads();
  for (int off = 1; off < 256; off <<= 1) {
    int u = (t >= off) ? sm[t - off] : 0;
    __syncthreads();
    sm[t] += u;
    __syncthreads();
  }
  bcur[255 - t] = sm[t] - v;
}
__global__ void bscatter_kernel(const int* __restrict__ deg, int* __restrict__ bcur,
                                int* __restrict__ perm, int n) {
  __shared__ int lh[256], lbase[256];
  int t = threadIdx.x;
  lh[t] = 0;
  __syncthreads();
  int i = blockIdx.x * 256 + t;
  int b = 0, local = 0;
  if (i < n) {
    b = min(deg[i], 255);
    local = atomicAdd(&lh[b], 1);
  }
  __syncthreads();
  int cnt = lh[t];
  lbase[t] = cnt ? atomicAdd(&bcur[t], cnt) : 0;
  __syncthreads();
  if (i < n) perm[lbase[b] + local] = i;
}

// ---------------- fp16 MFMA GEMM with LDS-transpose vectorized epilogue
// AMODE: 0 packed fp16 A; 1 fp32 row-major A (cvt); 2 pair-product gather
// CFG: 0 = 128m x 128n (2x2 waves); 1 = 256m x 64n (4x1 waves); 2 = 128m x 384n (2x2, 3 chunks)
// epi: 0 bias+relu->Ch, 1 kqv write (kw/mv interleaved fp16 + q fp16), 2 skip-mix(+relu),
//      3 bias+leaky->Ch, 4 bias+leaky+dot(W3)+b3 -> outd
template <int AMODE, int CFG>
__global__ __launch_bounds__(256) void gemm_mfma(
    const _Float16* __restrict__ Ah, const float* __restrict__ Af,
    const float* __restrict__ hsrc,
    const int* __restrict__ psrc, const int* __restrict__ pdst,
    const int* __restrict__ nsrc, const int* __restrict__ ndst,
    const _Float16* __restrict__ Bt,
    int M, int N, int K, int epi,
    const float* __restrict__ bias, const _Float16* __restrict__ hold,
    const float* __restrict__ skipv, int relu,
    float* __restrict__ Cf, _Float16* __restrict__ Ch, int Kout,
    const float* __restrict__ W3, const float* __restrict__ b3,
    float* __restrict__ outd, _Float16* __restrict__ kwmv, _Float16* __restrict__ qbuf) {
  constexpr int NCHUNK = (CFG == 2) ? 3 : 1;
  int tid = threadIdx.x;
  int wave = tid >> 6, lane = tid & 63;
  int l16 = lane & 15, q = lane >> 4;
  int m_base = (CFG == 1) ? (blockIdx.x * 256 + wave * 64)
                          : (blockIdx.x * 128 + (wave >> 1) * 64);
  int nw = (CFG == 1) ? 0 : (wave & 1) * 64;
  int kc_count = K >> 5;

  bool tv[4];
  int pa[4], pb[4], rowA[4];
  size_t a_base[4];
#pragma unroll
  for (int mt = 0; mt < 4; mt++) {
    int tile = (m_base >> 4) + mt;
    tv[mt] = (tile * 16) < M;
    if (AMODE == 0) {
      a_base[mt] = (size_t)(tv[mt] ? tile : 0) * ((size_t)kc_count << 9) + lane * 8;
    } else if (AMODE == 1) {
      rowA[mt] = min(m_base + mt * 16 + l16, M - 1);
    } else {
      int gr = min(m_base + mt * 16 + l16, M - 1);
      bool pos = gr < N_PAIRS;
      int idx = pos ? gr : gr - N_PAIRS;
      pa[mt] = pos ? psrc[idx] : nsrc[idx];
      pb[mt] = pos ? pdst[idx] : ndst[idx];
    }
  }

  // preload all A fragments (K <= 128 -> up to 4 k-chunks)
  half8v a[4][4];
#pragma unroll
  for (int kc = 0; kc < 4; kc++) {
    if (kc >= kc_count) break;
    int kbase = kc * 32 + q * 8;
#pragma unroll
    for (int mt = 0; mt < 4; mt++) {
      if (AMODE == 0) {
        if (tv[mt]) {
          a[mt][kc] = *(const half8v*)(Ah + a_base[mt] + (kc << 9));
        } else {
          a[mt][kc] = (half8v)(_Float16)0.f;
        }
      } else if (AMODE == 1) {
        const float* p = Af + (size_t)rowA[mt] * K + kbase;
        float4 u0 = *(const float4*)p, u1 = *(const float4*)(p + 4);
        float f[8] = {u0.x, u0.y, u0.z, u0.w, u1.x, u1.y, u1.z, u1.w};
        half8v hv;
#pragma unroll
        for (int i = 0; i < 8; i++) hv[i] = (_Float16)f[i];
        a[mt][kc] = hv;
      } else {
        const float* ra = hsrc + (size_t)pa[mt] * K + kbase;
        const float* rb = hsrc + (size_t)pb[mt] * K + kbase;
        float4 a0 = *(const float4*)ra, a1 = *(const float4*)(ra + 4);
        float4 c0 = *(const float4*)rb, c1 = *(const float4*)(rb + 4);
        float f[8] = {a0.x * c0.x, a0.y * c0.y, a0.z * c0.z, a0.w * c0.w,
                      a1.x * c1.x, a1.y * c1.y, a1.z * c1.z, a1.w * c1.w};
        half8v hv;
#pragma unroll
        for (int i = 0; i < 8; i++) hv[i] = (_Float16)f[i];
        a[mt][kc] = hv;
      }
    }
  }

  __shared__ float ldsT[4][16 * 68];
  float* myT = &ldsT[wave][0];
  float alpha = 1.f, beta = 0.f;
  if (epi == 2) {
    float sv = *skipv;
    alpha = 1.f / (1.f + __expf(-sv));
    beta = 1.f - alpha;
  }
  float b3v = (epi == 4) ? b3[0] : 0.f;
  int g = lane >> 4, mloc = lane & 15;

#pragma unroll
  for (int c = 0; c < NCHUNK; c++) {
    int nb_w = nw + c * 128;  // wave's col base (grids are all y=1)
    floatx4 acc[4][4];
#pragma unroll
    for (int i = 0; i < 4; i++)
#pragma unroll
      for (int j = 0; j < 4; j++) acc[i][j] = (floatx4){0.f, 0.f, 0.f, 0.f};
    size_t bb[4];
#pragma unroll
    for (int nt = 0; nt < 4; nt++)
      bb[nt] = (size_t)((nb_w >> 4) + nt) * ((size_t)kc_count << 9) + lane * 8;
#pragma unroll
    for (int kc = 0; kc < 4; kc++) {
      if (kc >= kc_count) break;
      half8v b[4];
#pragma unroll
      for (int nt = 0; nt < 4; nt++) b[nt] = *(const half8v*)(Bt + bb[nt] + (kc << 9));
#pragma unroll
      for (int mt = 0; mt < 4; mt++)
#pragma unroll
        for (int nt = 0; nt < 4; nt++)
          acc[mt][nt] = __builtin_amdgcn_mfma_f32_16x16x32_f16(a[mt][kc], b[nt],
                                                               acc[mt][nt], 0, 0, 0);
    }

    // ---- LDS-transpose epilogue
#pragma unroll
    for (int mt = 0; mt < 4; mt++) {
      int row0 = m_base + mt * 16;
#pragma unroll
      for (int nt = 0; nt < 4; nt++)
#pragma unroll
        for (int r = 0; r < 4; r++)
          myT[(q * 4 + r) * 68 + nt * 16 + l16] = acc[mt][nt][r];
      __syncthreads();
      if (tv[mt]) {
        int row = row0 + mloc;
        float outacc = 0.f;
#pragma unroll
        for (int kc2 = 0; kc2 < 2; kc2++) {
          const float* rp = myT + mloc * 68 + kc2 * 32 + g * 8;
          floatx4 v0 = *(const floatx4*)rp;
          floatx4 v1 = *(const floatx4*)(rp + 4);
          float vals[8] = {v0[0], v0[1], v0[2], v0[3], v1[0], v1[1], v1[2], v1[3]};
          int col0 = nb_w + kc2 * 32 + g * 8;
          size_t pbase = ((size_t)((row0 >> 4) * (Kout >> 5) + (col0 >> 5)) << 9) +
                         (size_t)lane * 8;
          if (epi == 0) {
            float4 bb0 = *(const float4*)&bias[col0];
            float4 bb1 = *(const float4*)&bias[col0 + 4];
            float bbv[8] = {bb0.x, bb0.y, bb0.z, bb0.w, bb1.x, bb1.y, bb1.z, bb1.w};
#pragma unroll
            for (int j = 0; j < 8; j++) vals[j] = fmaxf(vals[j] + bbv[j], 0.f);
            store_h8(Ch, pbase, vals);
          } else if (epi == 1) {
            int region = col0 >> 7;  // 0 kw, 1 q, 2 mv
            if (region == 1) {
              half8v hv;
#pragma unroll
              for (int j = 0; j < 8; j++) hv[j] = (_Float16)vals[j];
              *(half8v*)&qbuf[(size_t)row * 128 + (col0 - 128)] = hv;
            } else {
              int cc = col0 & 127;
              size_t base = (size_t)row * 256 + (size_t)(cc >> 2) * 8 +
                            (region == 2 ? 4 : 0);
              half4v h0, h1;
#pragma unroll
              for (int j = 0; j < 4; j++) {
                h0[j] = (_Float16)vals[j];
                h1[j] = (_Float16)vals[j + 4];
              }
              *(half4v*)&kwmv[base] = h0;
              *(half4v*)&kwmv[base + 8] = h1;
            }
          } else if (epi == 2) {
            half8v hv = *(const half8v*)(hold + pbase);
#pragma unroll
            for (int j = 0; j < 8; j++) {
              vals[j] = alpha * vals[j] + beta * (float)hv[j];
              if (relu) vals[j] = fmaxf(vals[j], 0.f);
            }
            if (Cf) {
              *(float4*)&Cf[(size_t)row * N + col0] =
                  make_float4(vals[0], vals[1], vals[2], vals[3]);
              *(float4*)&Cf[(size_t)row * N + col0 + 4] =
                  make_float4(vals[4], vals[5], vals[6], vals[7]);
            }
            if (Ch) store_h8(Ch, pbase, vals);
          } else if (epi == 3) {
            float4 bb0 = *(const float4*)&bias[col0];
            float4 bb1 = *(const float4*)&bias[col0 + 4];
            float bbv[8] = {bb0.x, bb0.y, bb0.z, bb0.w, bb1.x, bb1.y, bb1.z, bb1.w};
#pragma unroll
            for (int j = 0; j < 8; j++) {
              float v = vals[j] + bbv[j];
              vals[j] = v > 0.f ? v : 0.2f * v;
            }
            store_h8(Ch, pbase, vals);
          } else {  // epi 4
            bool inb = col0 < N;
            float4 bb0 = inb ? *(const float4*)&bias[col0] : make_float4(0, 0, 0, 0);
            float4 bb1 = inb ? *(const float4*)&bias[col0 + 4] : make_float4(0, 0, 0, 0);
            float4 w0 = inb ? *(const float4*)&W3[col0] : make_float4(0, 0, 0, 0);
            float4 w1 = inb ? *(const float4*)&W3[col0 + 4] : make_float4(0, 0, 0, 0);
            float bbv[8] = {bb0.x, bb0.y, bb0.z, bb0.w, bb1.x, bb1.y, bb1.z, bb1.w};
            float ww[8] = {w0.x, w0.y, w0.z, w0.w, w1.x, w1.y, w1.z, w1.w};
#pragma unroll
            for (int j = 0; j < 8; j++) {
              float v = vals[j] + bbv[j];
              v = v > 0.f ? v : 0.2f * v;
              outacc += v * ww[j];
            }
          }
        }
        if (epi == 4) {
          outacc += __shfl_xor(outacc, 16);
          outacc += __shfl_xor(outacc, 32);
          if (lane < 16) outd[row0 + lane] = outacc + b3v;
        }
      }
      __syncthreads();
    }
  }
}

// ---------------- per-destination online-softmax aggregation
// interleaved kw|mv table: one 16B gather per edge per lane
__global__ __launch_bounds__(256) void edge_agg_kernel(
    const _Float16* __restrict__ kwmv, const _Float16* __restrict__ qbuf,
    const int* __restrict__ poffs, const int2* __restrict__ eld,
    const int* __restrict__ perm,
    _Float16* __restrict__ agg, int n) {
  int wslot = blockIdx.x * 4 + (threadIdx.x >> 6);
  int lane = threadIdx.x & 63;
  int hh = lane >> 5;
  int c4 = lane & 31;
  int ch = c4 << 2;
  for (int gw = wslot; gw < n; gw += 8192) {
    int node = perm[gw];
    half4v qv = *(const half4v*)&qbuf[(size_t)node * 128 + ch];
    half2v q01 = {qv[0], qv[1]}, q23 = {qv[2], qv[3]};
    float m = -1e30f, s = 0.f;
    float a0 = 0.f, a1 = 0.f, a2 = 0.f, a3 = 0.f;
    int beg = poffs[node], end = poffs[node + 1];
    for (int j = beg; j < end; j += 16) {
      int2 e[8];
      half8v kvmv[8];
#pragma unroll
      for (int i = 0; i < 8; i++) {
        e[i] = eld[j + 2 * i + hh];
        kvmv[i] = *(const half8v*)&kwmv[(size_t)max(e[i].x, 0) * 256 + (size_t)c4 * 8];
      }
      float p[8];
#pragma unroll
      for (int i = 0; i < 8; i++) {
        half2v k01 = {kvmv[i][0], kvmv[i][1]}, k23 = {kvmv[i][2], kvmv[i][3]};
        float d = __builtin_amdgcn_fdot2(
            k01, q01, __builtin_amdgcn_fdot2(k23, q23, 0.f, false), false);
        d += __shfl_xor(d, 1);
        d += __shfl_xor(d, 2);
        p[i] = (e[i].x >= 0) ? d : -1e30f;
      }
      float nm = m;
#pragma unroll
      for (int i = 0; i < 8; i++) nm = fmaxf(nm, p[i]);
      float sc = __expf(m - nm);
      float t[8];
      float ssum = 0.f;
#pragma unroll
      for (int i = 0; i < 8; i++) {
        t[i] = __expf(p[i] - nm);
        ssum += t[i];
      }
      s = s * sc + ssum;
      a0 *= sc; a1 *= sc; a2 *= sc; a3 *= sc;
#pragma unroll
      for (int i = 0; i < 8; i++) {
        float w = (e[i].x >= 0) ? __int_as_float(e[i].y) : 0.f;
        float f = t[i] * w;
        a0 += f * (float)kvmv[i][4];
        a1 += f * (float)kvmv[i][5];
        a2 += f * (float)kvmv[i][6];
        a3 += f * (float)kvmv[i][7];
      }
      m = nm;
    }
    // merge halves
    float mo = __shfl_xor(m, 32);
    float so = __shfl_xor(s, 32);
    float c0 = __shfl_xor(a0, 32), c1 = __shfl_xor(a1, 32);
    float c2 = __shfl_xor(a2, 32), c3 = __shfl_xor(a3, 32);
    float M = fmaxf(m, mo);
    float e1 = __expf(m - M), e2 = __expf(mo - M);
    float st = s * e1 + so * e2;
    float v0 = a0 * e1 + c0 * e2, v1 = a1 * e1 + c1 * e2;
    float v2 = a2 * e1 + c2 * e2, v3 = a3 * e1 + c3 * e2;
    float inv = (st > 0.f) ? 1.f / st : 0.f;
    if (hh == 0) {
      half4v out4;
      out4[0] = (_Float16)(v0 * inv);
      out4[1] = (_Float16)(v1 * inv);
      out4[2] = (_Float16)(v2 * inv);
      out4[3] = (_Float16)(v3 * inv);
      *(half4v*)&agg[packA(node, ch, 128)] = out4;
    }
  }
}

extern "C" void kernel_launch(void* const* d_in, const int* in_sizes, int n_in,
                              void* d_out, int out_size, void* d_ws, size_t ws_size,
                              hipStream_t stream) {
  const float* x        = (const float*)d_in[0];
  const int*   edge_src = (const int*)d_in[1];
  const int*   edge_dst = (const int*)d_in[2];
  const float* edge_w   = (const float*)d_in[3];
  const int*   pos_src  = (const int*)d_in[4];
  const int*   pos_dst  = (const int*)d_in[5];
  const int*   neg_src  = (const int*)d_in[6];
  const int*   neg_dst  = (const int*)d_in[7];
  const float* W_in     = (const float*)d_in[8];
  const float* b_in     = (const float*)d_in[9];
  const float* Wk       = (const float*)d_in[10];
  const float* Wq       = (const float*)d_in[11];
  const float* Wv       = (const float*)d_in[12];
  const float* att_w    = (const float*)d_in[13];
  const float* msg_w    = (const float*)d_in[14];
  const float* pri      = (const float*)d_in[15];
  const float* Wa       = (const float*)d_in[16];
  const float* skip     = (const float*)d_in[17];
  const float* W1       = (const float*)d_in[18];
  const float* b1       = (const float*)d_in[19];
  const float* W2       = (const float*)d_in[20];
  const float* b2       = (const float*)d_in[21];
  const float* W3       = (const float*)d_in[22];
  const float* b3       = (const float*)d_in[23];
  float* out = (float*)d_out;

  // ---- workspace layout (bytes), ~78 MB
  char* W = (char*)d_ws;
  _Float16*  qbuf   = (_Float16*)(W + 0);          // 12,800,000
  _Float16*  kwmv   = (_Float16*)(W + 12800000);   // 25,600,000
  _Float16*  hbuf   = (_Float16*)(W + 38400000);   // 12,800,000
  _Float16*  agg    = (_Float16*)(W + 51200000);   // 12,800,000
  _Float16*  Wint   = (_Float16*)(W + 64000000);   // 32,768
  _Float16*  Wcat   = (_Float16*)(W + 64032768);   // 294,912
  _Float16*  Waf    = (_Float16*)(W + 64327680);   // 98,304
  _Float16*  W1f    = (_Float16*)(W + 64425984);   // 16,384
  _Float16*  W2f    = (_Float16*)(W + 64442368);   // 8,192
  int2*      eld    = (int2*)(W + 64450560);       // 12,800,000 (padded-16 edges)
  int*       deg    = (int*)(W + 77250560);        // 200,000
  int*       poffs  = (int*)(W + 77450560);        // 200,016
  int*       cursor = (int*)(W + 77650576);        // 200,000
  int*       perm   = (int*)(W + 77850576);        // 200,000
  int*       bsum   = (int*)(W + 78050576);        // 1,024
  int*       boff   = (int*)(W + 78051600);        // 1,024
  int*       bh     = (int*)(W + 78052624);        // 1,024
  int*       bcur   = (int*)(W + 78053648);        // 1,024
  // alias: T1 (200000x64 fp16 = 25.6MB) over qbuf+kwmv (dead by predictor)
  _Float16* T1 = (_Float16*)(W + 0);
  float* hfinal = out + 2 * N_PAIRS;

  hipMemsetAsync(deg, 0, N_NODES * sizeof(int), stream);
  hipMemsetAsync(bh, 0, 1024, stream);
  hipMemsetAsync(eld, 0xFF, 12800000, stream);  // sentinel: src=-1

  wprep_kernel<<<880, 256, 0, stream>>>(W_in, Wk, Wq, Wv, att_w, msg_w, pri, Wa, W1, W2,
                                        Wint, Wcat, Waf, W1f, W2f);
  hist_kernel<<<(N_EDGES + 255) / 256, 256, 0, stream>>>(edge_dst, deg, N_EDGES);
  scanA_kernel<<<196, 256, 0, stream>>>(deg, poffs, bsum, N_NODES);
  scanB_kernel<<<1, 256, 0, stream>>>(bsum, boff, poffs, 196, N_NODES);
  scanC_kernel<<<196, 256, 0, stream>>>(poffs, boff, cursor, N_NODES);
  scatter_kernel<<<(N_EDGES + 255) / 256, 256, 0, stream>>>(
      edge_src, edge_dst, edge_w, cursor, eld, N_EDGES);
  bhist_kernel<<<196, 256, 0, stream>>>(deg, bh, N_NODES);
  bscan_kernel<<<1, 256, 0, stream>>>(bh, bcur);
  bscatter_kernel<<<196, 256, 0, stream>>>(deg, bcur, perm, N_NODES);

  // input projection: h = relu(x @ W_in + b_in) -> packed fp16
  gemm_mfma<1, 0><<<dim3(391, 1), 256, 0, stream>>>(
      nullptr, x, nullptr, nullptr, nullptr, nullptr, nullptr,
      Wint, N_NODES, 128, 128, 0, b_in, nullptr, nullptr, 0,
      nullptr, hbuf, 128, nullptr, nullptr, nullptr, nullptr, nullptr);

  for (int l = 0; l < 3; l++) {
    gemm_mfma<0, 2><<<dim3(391, 1), 256, 0, stream>>>(
        hbuf, nullptr, nullptr, nullptr, nullptr, nullptr, nullptr,
        Wcat + l * 49152, N_NODES, 384, 128, 1, nullptr, nullptr, nullptr, 0,
        nullptr, nullptr, 128, nullptr, nullptr, nullptr, kwmv, qbuf);
    edge_agg_kernel<<<2048, 256, 0, stream>>>(
        kwmv, qbuf, poffs, eld, perm, agg, N_NODES);
    int last = (l == 2);
    gemm_mfma<0, 0><<<dim3(391, 1), 256, 0, stream>>>(
        agg, nullptr, nullptr, nullptr, nullptr, nullptr, nullptr,
        Waf + l * 16384, N_NODES, 128, 128, 2, nullptr, hbuf, skip + l,
        last ? 0 : 1, last ? hfinal : nullptr, last ? nullptr : hbuf, 128,
        nullptr, nullptr, nullptr, nullptr, nullptr);
  }

  // predictor: one 200000-row pass (pos | neg)
  gemm_mfma<2, 1><<<dim3(782, 1), 256, 0, stream>>>(
      nullptr, nullptr, hfinal, pos_src, pos_dst, neg_src, neg_dst,
      W1f, 2 * N_PAIRS, 64, 128, 3, b1, nullptr, nullptr, 0,
      nullptr, T1, 64, nullptr, nullptr, nullptr, nullptr, nullptr);
  gemm_mfma<0, 1><<<dim3(782, 1), 256, 0, stream>>>(
      T1, nullptr, nullptr, nullptr, nullptr, nullptr, nullptr,
      W2f, 2 * N_PAIRS, 32, 64, 4, b2, nullptr, nullptr, 0,
      nullptr, nullptr, 64, W3, b3, out, nullptr, nullptr);
}

// Round 8
// 602.411 us; speedup vs baseline: 2.1345x; 1.0329x over previous
//
#include <hip/hip_runtime.h>
#include <cstddef>

#define N_NODES 50000
#define N_EDGES 800000
#define N_PAIRS 100000

typedef float floatx4 __attribute__((ext_vector_type(4)));
typedef _Float16 half2v __attribute__((ext_vector_type(2)));
typedef _Float16 half4v __attribute__((ext_vector_type(4)));
typedef _Float16 half8v __attribute__((ext_vector_type(8)));

// packed MFMA A/B-fragment layout: [tile16][kchunk32][lane][8] (elements = fp16)
__device__ inline size_t packA(int m, int k, int K) {
  return ((size_t)((m >> 4) * (K >> 5) + (k >> 5)) << 9) +
         ((((unsigned)k >> 3) & 3) << 7) + ((m & 15) << 3) + (k & 7);
}
__device__ inline void store_h8(_Float16* __restrict__ dst, size_t base, const float* vals) {
  half8v hv;
#pragma unroll
  for (int i = 0; i < 8; i++) hv[i] = (_Float16)vals[i];
  *(half8v*)(dst + base) = hv;
}

// ---------------- all-in-one weight prep (fold + transpose + pack, fp16)
__device__ inline float fold_val(int l, int r, int j, const float* Wk, const float* Wq,
                                 const float* Wv, const float* att, const float* msg,
                                 const float* pri) {
  if (j >= 128 && j < 256) return Wq[(l * 128 + r) * 128 + (j - 128)];
  int jj = j & 127, hh = jj >> 4, e = jj & 15;
  const float* W = (j < 128) ? Wk : Wv;
  const float* T = (j < 128) ? att : msg;
  float s = 0.f;
#pragma unroll
  for (int d = 0; d < 16; d++)
    s += W[(l * 128 + r) * 128 + hh * 16 + d] * T[((l * 8 + hh) * 16 + d) * 16 + e];
  if (j < 128) s *= pri[l * 8 + hh] * 0.25f;
  return s;
}

__global__ void wprep_kernel(const float* __restrict__ W_in, const float* __restrict__ Wk,
                             const float* __restrict__ Wq, const float* __restrict__ Wv,
                             const float* __restrict__ att, const float* __restrict__ msg,
                             const float* __restrict__ pri, const float* __restrict__ Wa,
                             const float* __restrict__ W1, const float* __restrict__ W2,
                             _Float16* Wint, _Float16* Wcat, _Float16* Waf,
                             _Float16* W1f, _Float16* W2f) {
  int gid = blockIdx.x * 256 + threadIdx.x;
  float v;
  _Float16* dt;
  size_t o;
  if (gid < 16384) {
    int n = gid >> 7, k = gid & 127;
    v = W_in[k * 128 + n];
    dt = Wint; o = packA(n, k, 128);
  } else if (gid < 163840) {
    int t = gid - 16384;
    int l = t / 49152, u = t - l * 49152;
    int n = u >> 7, k = u & 127;
    v = fold_val(l, k, n, Wk, Wq, Wv, att, msg, pri);
    dt = Wcat + (size_t)l * 49152;
    o = packA(n, k, 128);
  } else if (gid < 212992) {
    int t = gid - 163840;
    int l = t / 16384, u = t & 16383;
    int n = u >> 7, k = u & 127;
    v = Wa[(size_t)l * 16384 + k * 128 + n];
    dt = Waf + (size_t)l * 16384;
    o = packA(n, k, 128);
  } else if (gid < 221184) {
    int u = gid - 212992;
    int n = u >> 7, k = u & 127;
    v = W1[k * 64 + n];
    dt = W1f; o = packA(n, k, 128);
  } else if (gid < 225280) {
    int u = gid - 221184;
    int n = u >> 6, k = u & 63;
    v = (n < 32) ? W2[k * 32 + n] : 0.f;
    dt = W2f; o = packA(n, k, 64);
  } else {
    return;
  }
  dt[o] = (_Float16)v;
}

// ---------------- CSR build (padded to multiple of 16 per node)
__global__ void hist_kernel(const int* __restrict__ dst, int* __restrict__ deg, int E) {
  int g = blockIdx.x * blockDim.x + threadIdx.x;
  if (g < E) atomicAdd(&deg[dst[g]], 1);
}

__global__ void scanA_kernel(const int* __restrict__ deg, int* __restrict__ offs,
                             int* __restrict__ bsum, int n) {
  __shared__ int sm[256];
  int t = threadIdx.x;
  int i = blockIdx.x * 256 + t;
  int v = (i < n) ? ((deg[i] + 15) & ~15) : 0;
  sm[t] = v;
  __syncthreads();
  for (int off = 1; off < 256; off <<= 1) {
    int u = (t >= off) ? sm[t - off] : 0;
    __syncthreads();
    sm[t] += u;
    __syncthreads();
  }
  if (i < n) offs[i] = sm[t] - v;
  if (t == 255) bsum[blockIdx.x] = sm[255];
}

__global__ void scanB_kernel(const int* __restrict__ bsum, int* __restrict__ boff,
                             int* __restrict__ offs, int nb, int n) {
  __shared__ int sm[256];
  int t = threadIdx.x;
  int v = (t < nb) ? bsum[t] : 0;
  sm[t] = v;
  __syncthreads();
  for (int off = 1; off < 256; off <<= 1) {
    int u = (t >= off) ? sm[t - off] : 0;
    __syncthreads();
    sm[t] += u;
    __syncthreads();
  }
  boff[t] = sm[t] - v;
  if (t == nb - 1) offs[n] = sm[t];
}

__global__ void scanC_kernel(int* __restrict__ offs, const int* __restrict__ boff,
                             int* __restrict__ cursor, int n) {
  int i = blockIdx.x * 256 + threadIdx.x;
  if (i < n) {
    int o = offs[i] + boff[blockIdx.x];
    offs[i] = o;
    cursor[i] = o;
  }
}

__global__ void scatter_kernel(const int* __restrict__ src, const int* __restrict__ dst,
                               const float* __restrict__ w, int* __restrict__ cursor,
                               int2* __restrict__ eld, int E) {
  int g = blockIdx.x * blockDim.x + threadIdx.x;
  if (g < E) {
    int d = dst[g];
    int p = atomicAdd(&cursor[d], 1);
    eld[p] = make_int2(src[g], __float_as_int(w[g]));
  }
}

// ---------------- degree-descending node permutation (counting sort, 256 buckets)
__global__ void bhist_kernel(const int* __restrict__ deg, int* __restrict__ bh, int n) {
  __shared__ int lh[256];
  int t = threadIdx.x;
  lh[t] = 0;
  __syncthreads();
  int i = blockIdx.x * 256 + t;
  if (i < n) atomicAdd(&lh[min(deg[i], 255)], 1);
  __syncthreads();
  if (lh[t]) atomicAdd(&bh[t], lh[t]);
}
__global__ void bscan_kernel(const int* __restrict__ bh, int* __restrict__ bcur) {
  __shared__ int sm[256];
  int t = threadIdx.x;
  int v = bh[255 - t];
  sm[t] = v;
  __syncthreads();
  for (int off = 1; off < 256; off <<= 1) {
    int u = (t >= off) ? sm[t - off] : 0;
    __syncthreads();
    sm[t] += u;
    __syncthreads();
  }
  bcur[255 - t] = sm[t] - v;
}
__global__ void bscatter_kernel(const int* __restrict__ deg, int* __restrict__ bcur,
                                int* __restrict__ perm, int n) {
  __shared__ int lh[256], lbase[256];
  int t = threadIdx.x;
  lh[t] = 0;
  __syncthreads();
  int i = blockIdx.x * 256 + t;
  int b = 0, local = 0;
  if (i < n) {
    b = min(deg[i], 255);
    local = atomicAdd(&lh[b], 1);
  }
  __syncthreads();
  int cnt = lh[t];
  lbase[t] = cnt ? atomicAdd(&bcur[t], cnt) : 0;
  __syncthreads();
  if (i < n) perm[lbase[b] + local] = i;
}

// ---------------- fp16 MFMA GEMM, 32m x 64n wave tiles (block = 128m x 64n)
// AMODE: 0 packed fp16 A; 1 fp32 row-major A (cvt); 2 fp16 pair-product gather (hrow)
// epi: 0 bias+relu->Ch, 1 kqv write, 2 skip-mix(+relu)[+Cf fp32][+hrow fp16],
//      3 bias+leaky->Ch, 4 bias+leaky+dot(W3)+b3 -> outd (no LDS)
template <int AMODE>
__global__ __launch_bounds__(256) void gemm_mfma(
    const _Float16* __restrict__ Ah, const float* __restrict__ Af,
    const _Float16* __restrict__ hrow_src,
    const int* __restrict__ psrc, const int* __restrict__ pdst,
    const int* __restrict__ nsrc, const int* __restrict__ ndst,
    const _Float16* __restrict__ Bt,
    int M, int N, int K, int epi,
    const float* __restrict__ bias, const _Float16* __restrict__ hold,
    const float* __restrict__ skipv, int relu,
    float* __restrict__ Cf, _Float16* __restrict__ Ch, int Kout,
    const float* __restrict__ W3, const float* __restrict__ b3,
    float* __restrict__ outd, _Float16* __restrict__ kwmv, _Float16* __restrict__ qbuf,
    _Float16* __restrict__ hrow_out) {
  int tid = threadIdx.x;
  int wave = tid >> 6, lane = tid & 63;
  int l16 = lane & 15, q = lane >> 4;
  int m_base = blockIdx.x * 128 + wave * 32;
  int n_base = blockIdx.y * 64;
  int kc_count = K >> 5;

  bool tv[2];
  int pa[2], pb[2], rowA[2];
  size_t a_base[2];
#pragma unroll
  for (int mt = 0; mt < 2; mt++) {
    int tile = (m_base >> 4) + mt;
    tv[mt] = (tile * 16) < M;
    if (AMODE == 0) {
      a_base[mt] = (size_t)(tv[mt] ? tile : 0) * ((size_t)kc_count << 9) + lane * 8;
    } else if (AMODE == 1) {
      rowA[mt] = min(m_base + mt * 16 + l16, M - 1);
    } else {
      int gr = min(m_base + mt * 16 + l16, M - 1);
      bool pos = gr < N_PAIRS;
      int idx = pos ? gr : gr - N_PAIRS;
      pa[mt] = pos ? psrc[idx] : nsrc[idx];
      pb[mt] = pos ? pdst[idx] : ndst[idx];
    }
  }

  // preload A fragments (K <= 128 -> up to 4 k-chunks)
  half8v a[2][4];
#pragma unroll
  for (int kc = 0; kc < 4; kc++) {
    if (kc >= kc_count) break;
    int kbase = kc * 32 + q * 8;
#pragma unroll
    for (int mt = 0; mt < 2; mt++) {
      if (AMODE == 0) {
        a[mt][kc] = tv[mt] ? *(const half8v*)(Ah + a_base[mt] + (kc << 9))
                           : (half8v)(_Float16)0.f;
      } else if (AMODE == 1) {
        const float* p = Af + (size_t)rowA[mt] * K + kbase;
        float4 u0 = *(const float4*)p, u1 = *(const float4*)(p + 4);
        float f[8] = {u0.x, u0.y, u0.z, u0.w, u1.x, u1.y, u1.z, u1.w};
        half8v hv;
#pragma unroll
        for (int i = 0; i < 8; i++) hv[i] = (_Float16)f[i];
        a[mt][kc] = hv;
      } else {
        half8v ha = *(const half8v*)(hrow_src + (size_t)pa[mt] * 128 + kbase);
        half8v hb = *(const half8v*)(hrow_src + (size_t)pb[mt] * 128 + kbase);
        a[mt][kc] = ha * hb;
      }
    }
  }

  floatx4 acc[2][4];
#pragma unroll
  for (int i = 0; i < 2; i++)
#pragma unroll
    for (int j = 0; j < 4; j++) acc[i][j] = (floatx4){0.f, 0.f, 0.f, 0.f};
  size_t bb[4];
#pragma unroll
  for (int nt = 0; nt < 4; nt++)
    bb[nt] = (size_t)((n_base >> 4) + nt) * ((size_t)kc_count << 9) + lane * 8;
#pragma unroll
  for (int kc = 0; kc < 4; kc++) {
    if (kc >= kc_count) break;
    half8v b[4];
#pragma unroll
    for (int nt = 0; nt < 4; nt++) b[nt] = *(const half8v*)(Bt + bb[nt] + (kc << 9));
#pragma unroll
    for (int mt = 0; mt < 2; mt++)
#pragma unroll
      for (int nt = 0; nt < 4; nt++)
        acc[mt][nt] = __builtin_amdgcn_mfma_f32_16x16x32_f16(a[mt][kc], b[nt],
                                                             acc[mt][nt], 0, 0, 0);
  }

  if (epi == 4) {
    // pre-transpose dot with W3: no LDS, no syncthreads
    float b3v = b3[0];
    float bw[4], wv[4];
#pragma unroll
    for (int nt = 0; nt < 4; nt++) {
      int col = n_base + nt * 16 + l16;
      bool inb = col < N;
      bw[nt] = inb ? bias[col] : 0.f;
      wv[nt] = inb ? W3[col] : 0.f;
    }
#pragma unroll
    for (int mt = 0; mt < 2; mt++) {
      if (!tv[mt]) continue;
#pragma unroll
      for (int r = 0; r < 4; r++) {
        float partial = 0.f;
#pragma unroll
        for (int nt = 0; nt < 4; nt++) {
          float v = acc[mt][nt][r] + bw[nt];
          v = v > 0.f ? v : 0.2f * v;
          partial += v * wv[nt];
        }
        partial += __shfl_xor(partial, 1);
        partial += __shfl_xor(partial, 2);
        partial += __shfl_xor(partial, 4);
        partial += __shfl_xor(partial, 8);
        int row = m_base + mt * 16 + q * 4 + r;
        if (l16 == 0 && row < M) outd[row] = partial + b3v;
      }
    }
    return;
  }

  // ---- LDS-transpose epilogue: lane ends with 8 consecutive cols of one row
  __shared__ float ldsT[4][16 * 68];
  float* myT = &ldsT[wave][0];
  float alpha = 1.f, beta = 0.f;
  if (epi == 2) {
    float sv = *skipv;
    alpha = 1.f / (1.f + __expf(-sv));
    beta = 1.f - alpha;
  }
  int g = lane >> 4, mloc = lane & 15;
#pragma unroll
  for (int mt = 0; mt < 2; mt++) {
    int row0 = m_base + mt * 16;
#pragma unroll
    for (int nt = 0; nt < 4; nt++)
#pragma unroll
      for (int r = 0; r < 4; r++)
        myT[(q * 4 + r) * 68 + nt * 16 + l16] = acc[mt][nt][r];
    __syncthreads();
    if (tv[mt]) {
      int row = row0 + mloc;
#pragma unroll
      for (int kc2 = 0; kc2 < 2; kc2++) {
        const float* rp = myT + mloc * 68 + kc2 * 32 + g * 8;
        floatx4 v0 = *(const floatx4*)rp;
        floatx4 v1 = *(const floatx4*)(rp + 4);
        float vals[8] = {v0[0], v0[1], v0[2], v0[3], v1[0], v1[1], v1[2], v1[3]};
        int col0 = n_base + kc2 * 32 + g * 8;
        size_t pbase = ((size_t)((row0 >> 4) * (Kout >> 5) + (col0 >> 5)) << 9) +
                       (size_t)lane * 8;
        if (epi == 0) {
          float4 bb0 = *(const float4*)&bias[col0];
          float4 bb1 = *(const float4*)&bias[col0 + 4];
          float bbv[8] = {bb0.x, bb0.y, bb0.z, bb0.w, bb1.x, bb1.y, bb1.z, bb1.w};
#pragma unroll
          for (int j = 0; j < 8; j++) vals[j] = fmaxf(vals[j] + bbv[j], 0.f);
          store_h8(Ch, pbase, vals);
        } else if (epi == 1) {
          int region = col0 >> 7;  // 0 kw, 1 q, 2 mv
          if (region == 1) {
            half8v hv;
#pragma unroll
            for (int j = 0; j < 8; j++) hv[j] = (_Float16)vals[j];
            *(half8v*)&qbuf[(size_t)row * 128 + (col0 - 128)] = hv;
          } else {
            int cc = col0 & 127;
            size_t base = (size_t)row * 256 + (size_t)(cc >> 2) * 8 +
                          (region == 2 ? 4 : 0);
            half4v h0, h1;
#pragma unroll
            for (int j = 0; j < 4; j++) {
              h0[j] = (_Float16)vals[j];
              h1[j] = (_Float16)vals[j + 4];
            }
            *(half4v*)&kwmv[base] = h0;
            *(half4v*)&kwmv[base + 8] = h1;
          }
        } else if (epi == 2) {
          half8v hv = *(const half8v*)(hold + pbase);
#pragma unroll
          for (int j = 0; j < 8; j++) {
            vals[j] = alpha * vals[j] + beta * (float)hv[j];
            if (relu) vals[j] = fmaxf(vals[j], 0.f);
          }
          if (Cf) {
            *(float4*)&Cf[(size_t)row * N + col0] =
                make_float4(vals[0], vals[1], vals[2], vals[3]);
            *(float4*)&Cf[(size_t)row * N + col0 + 4] =
                make_float4(vals[4], vals[5], vals[6], vals[7]);
          }
          if (Ch) store_h8(Ch, pbase, vals);
          if (hrow_out) store_h8(hrow_out, (size_t)row * 128 + col0, vals);
        } else {  // epi 3
          float4 bb0 = *(const float4*)&bias[col0];
          float4 bb1 = *(const float4*)&bias[col0 + 4];
          float bbv[8] = {bb0.x, bb0.y, bb0.z, bb0.w, bb1.x, bb1.y, bb1.z, bb1.w};
#pragma unroll
          for (int j = 0; j < 8; j++) {
            float v = vals[j] + bbv[j];
            vals[j] = v > 0.f ? v : 0.2f * v;
          }
          store_h8(Ch, pbase, vals);
        }
      }
    }
    __syncthreads();
  }
}

// ---------------- per-destination online-softmax aggregation
__global__ __launch_bounds__(256) void edge_agg_kernel(
    const _Float16* __restrict__ kwmv, const _Float16* __restrict__ qbuf,
    const int* __restrict__ poffs, const int2* __restrict__ eld,
    const int* __restrict__ perm,
    _Float16* __restrict__ agg, int n) {
  int wslot = blockIdx.x * 4 + (threadIdx.x >> 6);
  int lane = threadIdx.x & 63;
  int hh = lane >> 5;
  int c4 = lane & 31;
  int ch = c4 << 2;
  for (int gw = wslot; gw < n; gw += 8192) {
    int node = perm[gw];
    half4v qv = *(const half4v*)&qbuf[(size_t)node * 128 + ch];
    half2v q01 = {qv[0], qv[1]}, q23 = {qv[2], qv[3]};
    float m = -1e30f, s = 0.f;
    float a0 = 0.f, a1 = 0.f, a2 = 0.f, a3 = 0.f;
    int beg = poffs[node], end = poffs[node + 1];
    for (int j = beg; j < end; j += 16) {
      int2 e[8];
      half8v kvmv[8];
#pragma unroll
      for (int i = 0; i < 8; i++) {
        e[i] = eld[j + 2 * i + hh];
        kvmv[i] = *(const half8v*)&kwmv[(size_t)max(e[i].x, 0) * 256 + (size_t)c4 * 8];
      }
      float p[8];
#pragma unroll
      for (int i = 0; i < 8; i++) {
        half2v k01 = {kvmv[i][0], kvmv[i][1]}, k23 = {kvmv[i][2], kvmv[i][3]};
        float d = __builtin_amdgcn_fdot2(
            k01, q01, __builtin_amdgcn_fdot2(k23, q23, 0.f, false), false);
        d += __shfl_xor(d, 1);
        d += __shfl_xor(d, 2);
        p[i] = (e[i].x >= 0) ? d : -1e30f;
      }
      float nm = m;
#pragma unroll
      for (int i = 0; i < 8; i++) nm = fmaxf(nm, p[i]);
      float sc = __expf(m - nm);
      float t[8];
      float ssum = 0.f;
#pragma unroll
      for (int i = 0; i < 8; i++) {
        t[i] = __expf(p[i] - nm);
        ssum += t[i];
      }
      s = s * sc + ssum;
      a0 *= sc; a1 *= sc; a2 *= sc; a3 *= sc;
#pragma unroll
      for (int i = 0; i < 8; i++) {
        float w = (e[i].x >= 0) ? __int_as_float(e[i].y) : 0.f;
        float f = t[i] * w;
        a0 += f * (float)kvmv[i][4];
        a1 += f * (float)kvmv[i][5];
        a2 += f * (float)kvmv[i][6];
        a3 += f * (float)kvmv[i][7];
      }
      m = nm;
    }
    float mo = __shfl_xor(m, 32);
    float so = __shfl_xor(s, 32);
    float c0 = __shfl_xor(a0, 32), c1 = __shfl_xor(a1, 32);
    float c2 = __shfl_xor(a2, 32), c3 = __shfl_xor(a3, 32);
    float M = fmaxf(m, mo);
    float e1 = __expf(m - M), e2 = __expf(mo - M);
    float st = s * e1 + so * e2;
    float v0 = a0 * e1 + c0 * e2, v1 = a1 * e1 + c1 * e2;
    float v2 = a2 * e1 + c2 * e2, v3 = a3 * e1 + c3 * e2;
    float inv = (st > 0.f) ? 1.f / st : 0.f;
    if (hh == 0) {
      half4v out4;
      out4[0] = (_Float16)(v0 * inv);
      out4[1] = (_Float16)(v1 * inv);
      out4[2] = (_Float16)(v2 * inv);
      out4[3] = (_Float16)(v3 * inv);
      *(half4v*)&agg[packA(node, ch, 128)] = out4;
    }
  }
}

extern "C" void kernel_launch(void* const* d_in, const int* in_sizes, int n_in,
                              void* d_out, int out_size, void* d_ws, size_t ws_size,
                              hipStream_t stream) {
  const float* x        = (const float*)d_in[0];
  const int*   edge_src = (const int*)d_in[1];
  const int*   edge_dst = (const int*)d_in[2];
  const float* edge_w   = (const float*)d_in[3];
  const int*   pos_src  = (const int*)d_in[4];
  const int*   pos_dst  = (const int*)d_in[5];
  const int*   neg_src  = (const int*)d_in[6];
  const int*   neg_dst  = (const int*)d_in[7];
  const float* W_in     = (const float*)d_in[8];
  const float* b_in     = (const float*)d_in[9];
  const float* Wk       = (const float*)d_in[10];
  const float* Wq       = (const float*)d_in[11];
  const float* Wv       = (const float*)d_in[12];
  const float* att_w    = (const float*)d_in[13];
  const float* msg_w    = (const float*)d_in[14];
  const float* pri      = (const float*)d_in[15];
  const float* Wa       = (const float*)d_in[16];
  const float* skip     = (const float*)d_in[17];
  const float* W1       = (const float*)d_in[18];
  const float* b1       = (const float*)d_in[19];
  const float* W2       = (const float*)d_in[20];
  const float* b2       = (const float*)d_in[21];
  const float* W3       = (const float*)d_in[22];
  const float* b3       = (const float*)d_in[23];
  float* out = (float*)d_out;

  // ---- workspace layout (bytes), ~91 MB
  char* W = (char*)d_ws;
  _Float16*  qbuf   = (_Float16*)(W + 0);          // 12,800,000
  _Float16*  kwmv   = (_Float16*)(W + 12800000);   // 25,600,000
  _Float16*  hbuf   = (_Float16*)(W + 38400000);   // 12,800,000
  _Float16*  agg    = (_Float16*)(W + 51200000);   // 12,800,000
  _Float16*  Wint   = (_Float16*)(W + 64000000);   // 32,768
  _Float16*  Wcat   = (_Float16*)(W + 64032768);   // 294,912
  _Float16*  Waf    = (_Float16*)(W + 64327680);   // 98,304
  _Float16*  W1f    = (_Float16*)(W + 64425984);   // 16,384
  _Float16*  W2f    = (_Float16*)(W + 64442368);   // 8,192
  int2*      eld    = (int2*)(W + 64450560);       // 12,800,000 (padded-16 edges)
  int*       deg    = (int*)(W + 77250560);        // 200,000
  int*       poffs  = (int*)(W + 77450560);        // 200,016
  int*       cursor = (int*)(W + 77650576);        // 200,000
  int*       perm   = (int*)(W + 77850576);        // 200,000
  int*       bsum   = (int*)(W + 78050576);        // 1,024
  int*       boff   = (int*)(W + 78051600);        // 1,024
  int*       bh     = (int*)(W + 78052624);        // 1,024
  int*       bcur   = (int*)(W + 78053648);        // 1,024
  _Float16*  hrow   = (_Float16*)(W + 78054912);   // 12,800,000 (fp16 row-major h final)
  // alias: T1 (200000x64 fp16 = 25.6MB) over qbuf+kwmv (dead by predictor)
  _Float16* T1 = (_Float16*)(W + 0);
  float* hfinal = out + 2 * N_PAIRS;

  hipMemsetAsync(deg, 0, N_NODES * sizeof(int), stream);
  hipMemsetAsync(bh, 0, 1024, stream);
  hipMemsetAsync(eld, 0xFF, 12800000, stream);  // sentinel: src=-1

  wprep_kernel<<<880, 256, 0, stream>>>(W_in, Wk, Wq, Wv, att_w, msg_w, pri, Wa, W1, W2,
                                        Wint, Wcat, Waf, W1f, W2f);
  hist_kernel<<<(N_EDGES + 255) / 256, 256, 0, stream>>>(edge_dst, deg, N_EDGES);
  scanA_kernel<<<196, 256, 0, stream>>>(deg, poffs, bsum, N_NODES);
  scanB_kernel<<<1, 256, 0, stream>>>(bsum, boff, poffs, 196, N_NODES);
  scanC_kernel<<<196, 256, 0, stream>>>(poffs, boff, cursor, N_NODES);
  scatter_kernel<<<(N_EDGES + 255) / 256, 256, 0, stream>>>(
      edge_src, edge_dst, edge_w, cursor, eld, N_EDGES);
  bhist_kernel<<<196, 256, 0, stream>>>(deg, bh, N_NODES);
  bscan_kernel<<<1, 256, 0, stream>>>(bh, bcur);
  bscatter_kernel<<<196, 256, 0, stream>>>(deg, bcur, perm, N_NODES);

  // input projection: h = relu(x @ W_in + b_in) -> packed fp16
  gemm_mfma<1><<<dim3(391, 2), 256, 0, stream>>>(
      nullptr, x, nullptr, nullptr, nullptr, nullptr, nullptr,
      Wint, N_NODES, 128, 128, 0, b_in, nullptr, nullptr, 0,
      nullptr, hbuf, 128, nullptr, nullptr, nullptr, nullptr, nullptr, nullptr);

  for (int l = 0; l < 3; l++) {
    gemm_mfma<0><<<dim3(391, 6), 256, 0, stream>>>(
        hbuf, nullptr, nullptr, nullptr, nullptr, nullptr, nullptr,
        Wcat + l * 49152, N_NODES, 384, 128, 1, nullptr, nullptr, nullptr, 0,
        nullptr, nullptr, 128, nullptr, nullptr, nullptr, kwmv, qbuf, nullptr);
    edge_agg_kernel<<<2048, 256, 0, stream>>>(
        kwmv, qbuf, poffs, eld, perm, agg, N_NODES);
    int last = (l == 2);
    gemm_mfma<0><<<dim3(391, 2), 256, 0, stream>>>(
        agg, nullptr, nullptr, nullptr, nullptr, nullptr, nullptr,
        Waf + l * 16384, N_NODES, 128, 128, 2, nullptr, hbuf, skip + l,
        last ? 0 : 1, last ? hfinal : nullptr, last ? nullptr : hbuf, 128,
        nullptr, nullptr, nullptr, nullptr, nullptr, last ? hrow : nullptr);
  }

  // predictor: one 200000-row pass (pos | neg)
  gemm_mfma<2><<<dim3(1563, 1), 256, 0, stream>>>(
      nullptr, nullptr, hrow, pos_src, pos_dst, neg_src, neg_dst,
      W1f, 2 * N_PAIRS, 64, 128, 3, b1, nullptr, nullptr, 0,
      nullptr, T1, 64, nullptr, nullptr, nullptr, nullptr, nullptr, nullptr);
  gemm_mfma<0><<<dim3(1563, 1), 256, 0, stream>>>(
      T1, nullptr, nullptr, nullptr, nullptr, nullptr, nullptr,
      W2f, 2 * N_PAIRS, 32, 64, 4, b2, nullptr, nullptr, 0,
      nullptr, nullptr, 64, W3, b3, out, nullptr, nullptr, nullptr);
}

// Round 9
// 561.460 us; speedup vs baseline: 2.2901x; 1.0729x over previous
//
#include <hip/hip_runtime.h>
#include <cstddef>

#define N_NODES 50000
#define N_EDGES 800000
#define N_PAIRS 100000

typedef float floatx4 __attribute__((ext_vector_type(4)));
typedef _Float16 half2v __attribute__((ext_vector_type(2)));
typedef _Float16 half4v __attribute__((ext_vector_type(4)));
typedef _Float16 half8v __attribute__((ext_vector_type(8)));

// packed MFMA A/B-fragment layout: [tile16][kchunk32][lane][8] (fp16)
__device__ inline size_t packA(int m, int k, int K) {
  return ((size_t)((m >> 4) * (K >> 5) + (k >> 5)) << 9) +
         ((((unsigned)k >> 3) & 3) << 7) + ((m & 15) << 3) + (k & 7);
}

// ---------------- weight prep (fold + transpose + pack, fp16)
__device__ inline float fold_val(int l, int r, int j, const float* Wk, const float* Wq,
                                 const float* Wv, const float* att, const float* msg,
                                 const float* pri) {
  if (j >= 128 && j < 256) return Wq[(l * 128 + r) * 128 + (j - 128)];
  int jj = j & 127, hh = jj >> 4, e = jj & 15;
  const float* W = (j < 128) ? Wk : Wv;
  const float* T = (j < 128) ? att : msg;
  float s = 0.f;
#pragma unroll
  for (int d = 0; d < 16; d++)
    s += W[(l * 128 + r) * 128 + hh * 16 + d] * T[((l * 8 + hh) * 16 + d) * 16 + e];
  if (j < 128) s *= pri[l * 8 + hh] * 0.25f;
  return s;
}

__global__ void wprep_kernel(const float* __restrict__ W_in, const float* __restrict__ Wk,
                             const float* __restrict__ Wq, const float* __restrict__ Wv,
                             const float* __restrict__ att, const float* __restrict__ msg,
                             const float* __restrict__ pri, const float* __restrict__ Wa,
                             const float* __restrict__ W1, const float* __restrict__ W2,
                             _Float16* Wint, _Float16* Wcat, _Float16* Waf,
                             _Float16* W1f, _Float16* W2f) {
  int gid = blockIdx.x * 256 + threadIdx.x;
  float v;
  _Float16* dt;
  size_t o;
  if (gid < 16384) {
    int n = gid >> 7, k = gid & 127;
    v = W_in[k * 128 + n];
    dt = Wint; o = packA(n, k, 128);
  } else if (gid < 163840) {
    int t = gid - 16384;
    int l = t / 49152, u = t - l * 49152;
    int n = u >> 7, k = u & 127;
    v = fold_val(l, k, n, Wk, Wq, Wv, att, msg, pri);
    dt = Wcat + (size_t)l * 49152;
    o = packA(n, k, 128);
  } else if (gid < 212992) {
    int t = gid - 163840;
    int l = t / 16384, u = t & 16383;
    int n = u >> 7, k = u & 127;
    v = Wa[(size_t)l * 16384 + k * 128 + n];
    dt = Waf + (size_t)l * 16384;
    o = packA(n, k, 128);
  } else if (gid < 221184) {
    int u = gid - 212992;
    int n = u >> 7, k = u & 127;
    v = W1[k * 64 + n];
    dt = W1f; o = packA(n, k, 128);
  } else if (gid < 225280) {
    int u = gid - 221184;
    int n = u >> 6, k = u & 63;
    v = (n < 32) ? W2[k * 32 + n] : 0.f;
    dt = W2f; o = packA(n, k, 64);
  } else {
    return;
  }
  dt[o] = (_Float16)v;
}

// ---------------- CSR build (padded to multiple of 16 per node)
__global__ void hist_kernel(const int* __restrict__ dst, int* __restrict__ deg, int E) {
  int g = blockIdx.x * blockDim.x + threadIdx.x;
  if (g < E) atomicAdd(&deg[dst[g]], 1);
}

__global__ void scanA_kernel(const int* __restrict__ deg, int* __restrict__ offs,
                             int* __restrict__ bsum, int n) {
  __shared__ int sm[256];
  int t = threadIdx.x;
  int i = blockIdx.x * 256 + t;
  int v = (i < n) ? ((deg[i] + 15) & ~15) : 0;
  sm[t] = v;
  __syncthreads();
  for (int off = 1; off < 256; off <<= 1) {
    int u = (t >= off) ? sm[t - off] : 0;
    __syncthreads();
    sm[t] += u;
    __syncthreads();
  }
  if (i < n) offs[i] = sm[t] - v;
  if (t == 255) bsum[blockIdx.x] = sm[255];
}

__global__ void scanB_kernel(const int* __restrict__ bsum, int* __restrict__ boff,
                             int* __restrict__ offs, int nb, int n) {
  __shared__ int sm[256];
  int t = threadIdx.x;
  int v = (t < nb) ? bsum[t] : 0;
  sm[t] = v;
  __syncthreads();
  for (int off = 1; off < 256; off <<= 1) {
    int u = (t >= off) ? sm[t - off] : 0;
    __syncthreads();
    sm[t] += u;
    __syncthreads();
  }
  boff[t] = sm[t] - v;
  if (t == nb - 1) offs[n] = sm[t];
}

__global__ void scanC_kernel(int* __restrict__ offs, const int* __restrict__ boff,
                             int* __restrict__ cursor, int n) {
  int i = blockIdx.x * 256 + threadIdx.x;
  if (i < n) {
    int o = offs[i] + boff[blockIdx.x];
    offs[i] = o;
    cursor[i] = o;
  }
}

__global__ void scatter_kernel(const int* __restrict__ src, const int* __restrict__ dst,
                               const float* __restrict__ w, int* __restrict__ cursor,
                               int2* __restrict__ eld, int E) {
  int g = blockIdx.x * blockDim.x + threadIdx.x;
  if (g < E) {
    int d = dst[g];
    int p = atomicAdd(&cursor[d], 1);
    eld[p] = make_int2(src[g], __float_as_int(w[g]));
  }
}

// ---------------- degree-descending node permutation (counting sort, 256 buckets)
__global__ void bhist_kernel(const int* __restrict__ deg, int* __restrict__ bh, int n) {
  __shared__ int lh[256];
  int t = threadIdx.x;
  lh[t] = 0;
  __syncthreads();
  int i = blockIdx.x * 256 + t;
  if (i < n) atomicAdd(&lh[min(deg[i], 255)], 1);
  __syncthreads();
  if (lh[t]) atomicAdd(&bh[t], lh[t]);
}
__global__ void bscan_kernel(const int* __restrict__ bh, int* __restrict__ bcur) {
  __shared__ int sm[256];
  int t = threadIdx.x;
  int v = bh[255 - t];
  sm[t] = v;
  __syncthreads();
  for (int off = 1; off < 256; off <<= 1) {
    int u = (t >= off) ? sm[t - off] : 0;
    __syncthreads();
    sm[t] += u;
    __syncthreads();
  }
  bcur[255 - t] = sm[t] - v;
}
__global__ void bscatter_kernel(const int* __restrict__ deg, int* __restrict__ bcur,
                                int* __restrict__ perm, int n) {
  __shared__ int lh[256], lbase[256];
  int t = threadIdx.x;
  lh[t] = 0;
  __syncthreads();
  int i = blockIdx.x * 256 + t;
  int b = 0, local = 0;
  if (i < n) {
    b = min(deg[i], 255);
    local = atomicAdd(&lh[b], 1);
  }
  __syncthreads();
  int cnt = lh[t];
  lbase[t] = cnt ? atomicAdd(&bcur[t], cnt) : 0;
  __syncthreads();
  if (i < n) perm[lbase[b] + local] = i;
}

// ---------------- fused layer kernel: GEMM1 (h) -> LDS fragments -> GEMM2 (kqv)
// FIRST=1: h = relu(x @ Wg1 + bias); FIRST=0: h = mix(agg @ Wg1, hold=hbuf) + relu
// then kqv = h @ Wcat -> kwmv/qbuf; h also written packed to hbuf (next layer's hold)
template <int FIRST>
__global__ __launch_bounds__(256) void fused_layer(
    const float* __restrict__ x, const _Float16* __restrict__ aggp,
    const _Float16* __restrict__ Wg1, const float* __restrict__ bias,
    const float* __restrict__ skipv, _Float16* __restrict__ hbuf,
    const _Float16* __restrict__ Wcat_l,
    _Float16* __restrict__ kwmv, _Float16* __restrict__ qbuf, int M) {
  int tid = threadIdx.x;
  int wave = tid >> 6, lane = tid & 63;
  int l16 = lane & 15, q = lane >> 4;
  int g = q, mloc = l16;
  int tile = blockIdx.x * 4 + wave;
  int m0 = tile * 16;
  bool alive = m0 < M;
  int tileC = alive ? tile : 0;

  __shared__ _Float16 htile_s[4][2048];
  __shared__ float ldsT_s[4][16 * 68];
  _Float16* htile = htile_s[wave];
  float* myT = ldsT_s[wave];

  // GEMM1 A fragments
  half8v a[4];
#pragma unroll
  for (int kc = 0; kc < 4; kc++) {
    if (FIRST) {
      int row = min(m0 + l16, M - 1);
      const float* p = x + (size_t)row * 128 + kc * 32 + q * 8;
      float4 u0 = *(const float4*)p, u1 = *(const float4*)(p + 4);
      float f[8] = {u0.x, u0.y, u0.z, u0.w, u1.x, u1.y, u1.z, u1.w};
      half8v hv;
#pragma unroll
      for (int i = 0; i < 8; i++) hv[i] = (_Float16)f[i];
      a[kc] = hv;
    } else {
      a[kc] = *(const half8v*)(aggp + (size_t)tileC * 2048 + (kc << 9) + lane * 8);
    }
  }

  float alpha = 1.f, beta = 0.f;
  if (!FIRST) {
    float sv = *skipv;
    alpha = 1.f / (1.f + __expf(-sv));
    beta = 1.f - alpha;
  }

  floatx4 acc1[8];
#pragma unroll
  for (int nt = 0; nt < 8; nt++) acc1[nt] = (floatx4){0.f, 0.f, 0.f, 0.f};
#pragma unroll
  for (int kc = 0; kc < 4; kc++) {
    half8v b[8];
#pragma unroll
    for (int nt = 0; nt < 8; nt++)
      b[nt] = *(const half8v*)(Wg1 + (size_t)nt * 2048 + (kc << 9) + lane * 8);
#pragma unroll
    for (int nt = 0; nt < 8; nt++)
      acc1[nt] = __builtin_amdgcn_mfma_f32_16x16x32_f16(a[kc], b[nt], acc1[nt], 0, 0, 0);
  }

  // epilogue1: per-64-col transpose; emit packed hbuf + LDS h-tile fragments
#pragma unroll
  for (int p = 0; p < 2; p++) {
    __syncthreads();
#pragma unroll
    for (int ntl = 0; ntl < 4; ntl++)
#pragma unroll
      for (int r = 0; r < 4; r++)
        myT[(q * 4 + r) * 68 + ntl * 16 + l16] = acc1[p * 4 + ntl][r];
    __syncthreads();
#pragma unroll
    for (int kc2 = 0; kc2 < 2; kc2++) {
      const float* rp = myT + mloc * 68 + kc2 * 32 + g * 8;
      floatx4 v0 = *(const floatx4*)rp;
      floatx4 v1 = *(const floatx4*)(rp + 4);
      float vals[8] = {v0[0], v0[1], v0[2], v0[3], v1[0], v1[1], v1[2], v1[3]};
      int col0 = p * 64 + kc2 * 32 + g * 8;
      size_t pbaseL = ((size_t)(tileC * 4 + (col0 >> 5)) << 9) + (size_t)lane * 8;
      if (FIRST) {
        float4 bb0 = *(const float4*)&bias[col0];
        float4 bb1 = *(const float4*)&bias[col0 + 4];
        float bbv[8] = {bb0.x, bb0.y, bb0.z, bb0.w, bb1.x, bb1.y, bb1.z, bb1.w};
#pragma unroll
        for (int j = 0; j < 8; j++) vals[j] = fmaxf(vals[j] + bbv[j], 0.f);
      } else {
        half8v hv = *(const half8v*)(hbuf + pbaseL);
#pragma unroll
        for (int j = 0; j < 8; j++)
          vals[j] = fmaxf(alpha * vals[j] + beta * (float)hv[j], 0.f);
      }
      half8v h8;
#pragma unroll
      for (int j = 0; j < 8; j++) h8[j] = (_Float16)vals[j];
      *(half8v*)(htile + (((p * 2 + kc2) << 9) + (g << 7) + (mloc << 3))) = h8;
      if (alive) *(half8v*)(hbuf + pbaseL) = h8;
    }
  }

  // GEMM2: kqv = h-tile @ Wcat (384 cols, 6 chunks of 64)
  for (int c = 0; c < 6; c++) {
    floatx4 acc2[4];
#pragma unroll
    for (int nt = 0; nt < 4; nt++) acc2[nt] = (floatx4){0.f, 0.f, 0.f, 0.f};
#pragma unroll
    for (int kc = 0; kc < 4; kc++) {
      half8v af = *(const half8v*)(htile + ((kc << 9) + lane * 8));
      half8v b[4];
#pragma unroll
      for (int nt = 0; nt < 4; nt++)
        b[nt] = *(const half8v*)(Wcat_l + (size_t)(c * 4 + nt) * 2048 + (kc << 9) + lane * 8);
#pragma unroll
      for (int nt = 0; nt < 4; nt++)
        acc2[nt] = __builtin_amdgcn_mfma_f32_16x16x32_f16(af, b[nt], acc2[nt], 0, 0, 0);
    }
    __syncthreads();
#pragma unroll
    for (int ntl = 0; ntl < 4; ntl++)
#pragma unroll
      for (int r = 0; r < 4; r++)
        myT[(q * 4 + r) * 68 + ntl * 16 + l16] = acc2[ntl][r];
    __syncthreads();
    if (alive) {
      int row = m0 + mloc;
#pragma unroll
      for (int kc2 = 0; kc2 < 2; kc2++) {
        const float* rp = myT + mloc * 68 + kc2 * 32 + g * 8;
        floatx4 v0 = *(const floatx4*)rp;
        floatx4 v1 = *(const floatx4*)(rp + 4);
        int col0 = c * 64 + kc2 * 32 + g * 8;
        int region = col0 >> 7;  // 0 kw, 1 q, 2 mv
        if (region == 1) {
          half8v h8;
#pragma unroll
          for (int j = 0; j < 4; j++) {
            h8[j] = (_Float16)v0[j];
            h8[j + 4] = (_Float16)v1[j];
          }
          *(half8v*)&qbuf[(size_t)row * 128 + (col0 - 128)] = h8;
        } else {
          int cc = col0 & 127;
          size_t base = (size_t)row * 256 + (size_t)(cc >> 2) * 8 + (region == 2 ? 4 : 0);
          half4v h0, h1;
#pragma unroll
          for (int j = 0; j < 4; j++) {
            h0[j] = (_Float16)v0[j];
            h1[j] = (_Float16)v1[j];
          }
          *(half4v*)&kwmv[base] = h0;
          *(half4v*)&kwmv[base + 8] = h1;
        }
      }
    }
  }
}

// ---------------- last Wa GEMM: hfinal = mix(agg @ Wa2, hold) (no relu) + hrow fp16
__global__ __launch_bounds__(256) void gemm_last(
    const _Float16* __restrict__ aggp, const _Float16* __restrict__ Wg1,
    const float* __restrict__ skipv, const _Float16* __restrict__ hbuf,
    float* __restrict__ hfinal, _Float16* __restrict__ hrow, int M) {
  int tid = threadIdx.x;
  int wave = tid >> 6, lane = tid & 63;
  int l16 = lane & 15, q = lane >> 4;
  int g = q, mloc = l16;
  int tile = blockIdx.x * 4 + wave;
  int m0 = tile * 16;
  bool alive = m0 < M;
  int tileC = alive ? tile : 0;

  __shared__ float ldsT_s[4][16 * 68];
  float* myT = ldsT_s[wave];

  half8v a[4];
#pragma unroll
  for (int kc = 0; kc < 4; kc++)
    a[kc] = *(const half8v*)(aggp + (size_t)tileC * 2048 + (kc << 9) + lane * 8);

  float sv = *skipv;
  float alpha = 1.f / (1.f + __expf(-sv));
  float beta = 1.f - alpha;

  floatx4 acc1[8];
#pragma unroll
  for (int nt = 0; nt < 8; nt++) acc1[nt] = (floatx4){0.f, 0.f, 0.f, 0.f};
#pragma unroll
  for (int kc = 0; kc < 4; kc++) {
    half8v b[8];
#pragma unroll
    for (int nt = 0; nt < 8; nt++)
      b[nt] = *(const half8v*)(Wg1 + (size_t)nt * 2048 + (kc << 9) + lane * 8);
#pragma unroll
    for (int nt = 0; nt < 8; nt++)
      acc1[nt] = __builtin_amdgcn_mfma_f32_16x16x32_f16(a[kc], b[nt], acc1[nt], 0, 0, 0);
  }

#pragma unroll
  for (int p = 0; p < 2; p++) {
    __syncthreads();
#pragma unroll
    for (int ntl = 0; ntl < 4; ntl++)
#pragma unroll
      for (int r = 0; r < 4; r++)
        myT[(q * 4 + r) * 68 + ntl * 16 + l16] = acc1[p * 4 + ntl][r];
    __syncthreads();
    if (alive) {
      int row = m0 + mloc;
#pragma unroll
      for (int kc2 = 0; kc2 < 2; kc2++) {
        const float* rp = myT + mloc * 68 + kc2 * 32 + g * 8;
        floatx4 v0 = *(const floatx4*)rp;
        floatx4 v1 = *(const floatx4*)(rp + 4);
        float vals[8] = {v0[0], v0[1], v0[2], v0[3], v1[0], v1[1], v1[2], v1[3]};
        int col0 = p * 64 + kc2 * 32 + g * 8;
        size_t pbase = ((size_t)(tile * 4 + (col0 >> 5)) << 9) + (size_t)lane * 8;
        half8v hv = *(const half8v*)(hbuf + pbase);
#pragma unroll
        for (int j = 0; j < 8; j++) vals[j] = alpha * vals[j] + beta * (float)hv[j];
        *(float4*)&hfinal[(size_t)row * 128 + col0] =
            make_float4(vals[0], vals[1], vals[2], vals[3]);
        *(float4*)&hfinal[(size_t)row * 128 + col0 + 4] =
            make_float4(vals[4], vals[5], vals[6], vals[7]);
        half8v h8;
#pragma unroll
        for (int j = 0; j < 8; j++) h8[j] = (_Float16)vals[j];
        *(half8v*)&hrow[(size_t)row * 128 + col0] = h8;
      }
    }
  }
}

// ---------------- fused predictor: Z=h[a]*h[b] -> W1+leaky -> W2+leaky -> dot W3
__global__ __launch_bounds__(256) void pred_fused(
    const _Float16* __restrict__ hrow,
    const int* __restrict__ ps, const int* __restrict__ pd,
    const int* __restrict__ ns, const int* __restrict__ nd,
    const _Float16* __restrict__ W1f, const float* __restrict__ b1,
    const _Float16* __restrict__ W2f, const float* __restrict__ b2,
    const float* __restrict__ W3, const float* __restrict__ b3,
    float* __restrict__ outd, int M) {
  int tid = threadIdx.x;
  int wave = tid >> 6, lane = tid & 63;
  int l16 = lane & 15, q = lane >> 4;
  int g = q, mloc = l16;
  int tile = blockIdx.x * 4 + wave;
  int m0 = tile * 16;
  bool alive = m0 < M;

  __shared__ _Float16 t1_s[4][1024];
  __shared__ float ldsT_s[4][16 * 68];
  _Float16* t1tile = t1_s[wave];
  float* myT = ldsT_s[wave];

  int gr = min(m0 + l16, M - 1);
  bool pos = gr < N_PAIRS;
  int idx = pos ? gr : gr - N_PAIRS;
  int pa = pos ? ps[idx] : ns[idx];
  int pb = pos ? pd[idx] : nd[idx];

  half8v a[4];
#pragma unroll
  for (int kc = 0; kc < 4; kc++) {
    int kbase = kc * 32 + q * 8;
    half8v ha = *(const half8v*)(hrow + (size_t)pa * 128 + kbase);
    half8v hb = *(const half8v*)(hrow + (size_t)pb * 128 + kbase);
    a[kc] = ha * hb;
  }

  floatx4 acc1[4];
#pragma unroll
  for (int nt = 0; nt < 4; nt++) acc1[nt] = (floatx4){0.f, 0.f, 0.f, 0.f};
#pragma unroll
  for (int kc = 0; kc < 4; kc++) {
    half8v b[4];
#pragma unroll
    for (int nt = 0; nt < 4; nt++)
      b[nt] = *(const half8v*)(W1f + (size_t)nt * 2048 + (kc << 9) + lane * 8);
#pragma unroll
    for (int nt = 0; nt < 4; nt++)
      acc1[nt] = __builtin_amdgcn_mfma_f32_16x16x32_f16(a[kc], b[nt], acc1[nt], 0, 0, 0);
  }

  // epilogue1: bias+leaky -> per-wave T1 fragments (16 rows x 64 k)
  __syncthreads();
#pragma unroll
  for (int ntl = 0; ntl < 4; ntl++)
#pragma unroll
    for (int r = 0; r < 4; r++)
      myT[(q * 4 + r) * 68 + ntl * 16 + l16] = acc1[ntl][r];
  __syncthreads();
#pragma unroll
  for (int kc2 = 0; kc2 < 2; kc2++) {
    const float* rp = myT + mloc * 68 + kc2 * 32 + g * 8;
    floatx4 v0 = *(const floatx4*)rp;
    floatx4 v1 = *(const floatx4*)(rp + 4);
    float vals[8] = {v0[0], v0[1], v0[2], v0[3], v1[0], v1[1], v1[2], v1[3]};
    int col0 = kc2 * 32 + g * 8;
    float4 bb0 = *(const float4*)&b1[col0];
    float4 bb1 = *(const float4*)&b1[col0 + 4];
    float bbv[8] = {bb0.x, bb0.y, bb0.z, bb0.w, bb1.x, bb1.y, bb1.z, bb1.w};
    half8v h8;
#pragma unroll
    for (int j = 0; j < 8; j++) {
      float v = vals[j] + bbv[j];
      v = v > 0.f ? v : 0.2f * v;
      h8[j] = (_Float16)v;
    }
    *(half8v*)(t1tile + ((kc2 << 9) + (g << 7) + (mloc << 3))) = h8;
  }

  // GEMM2: T1 @ W2 (K=64, N=32) + leaky + dot W3
  floatx4 acc2[2];
#pragma unroll
  for (int nt = 0; nt < 2; nt++) acc2[nt] = (floatx4){0.f, 0.f, 0.f, 0.f};
#pragma unroll
  for (int kc = 0; kc < 2; kc++) {
    half8v af = *(const half8v*)(t1tile + ((kc << 9) + lane * 8));
    half8v b[2];
#pragma unroll
    for (int nt = 0; nt < 2; nt++)
      b[nt] = *(const half8v*)(W2f + (size_t)nt * 1024 + (kc << 9) + lane * 8);
#pragma unroll
    for (int nt = 0; nt < 2; nt++)
      acc2[nt] = __builtin_amdgcn_mfma_f32_16x16x32_f16(af, b[nt], acc2[nt], 0, 0, 0);
  }

  float bw[2], wv[2];
#pragma unroll
  for (int nt = 0; nt < 2; nt++) {
    int col = nt * 16 + l16;
    bw[nt] = b2[col];
    wv[nt] = W3[col];
  }
  float b3v = b3[0];
#pragma unroll
  for (int r = 0; r < 4; r++) {
    float partial = 0.f;
#pragma unroll
    for (int nt = 0; nt < 2; nt++) {
      float v = acc2[nt][r] + bw[nt];
      v = v > 0.f ? v : 0.2f * v;
      partial += v * wv[nt];
    }
    partial += __shfl_xor(partial, 1);
    partial += __shfl_xor(partial, 2);
    partial += __shfl_xor(partial, 4);
    partial += __shfl_xor(partial, 8);
    int row = m0 + q * 4 + r;
    if (l16 == 0 && alive && row < M) outd[row] = partial + b3v;
  }
}

// ---------------- per-destination online-softmax aggregation
__global__ __launch_bounds__(256) void edge_agg_kernel(
    const _Float16* __restrict__ kwmv, const _Float16* __restrict__ qbuf,
    const int* __restrict__ poffs, const int2* __restrict__ eld,
    const int* __restrict__ perm,
    _Float16* __restrict__ agg, int n) {
  int wslot = blockIdx.x * 4 + (threadIdx.x >> 6);
  int lane = threadIdx.x & 63;
  int hh = lane >> 5;
  int c4 = lane & 31;
  int ch = c4 << 2;
  for (int gw = wslot; gw < n; gw += 8192) {
    int node = perm[gw];
    half4v qv = *(const half4v*)&qbuf[(size_t)node * 128 + ch];
    half2v q01 = {qv[0], qv[1]}, q23 = {qv[2], qv[3]};
    float m = -1e30f, s = 0.f;
    float a0 = 0.f, a1 = 0.f, a2 = 0.f, a3 = 0.f;
    int beg = poffs[node], end = poffs[node + 1];
    for (int j = beg; j < end; j += 16) {
      int2 e[8];
      half8v kvmv[8];
#pragma unroll
      for (int i = 0; i < 8; i++) {
        e[i] = eld[j + 2 * i + hh];
        kvmv[i] = *(const half8v*)&kwmv[(size_t)max(e[i].x, 0) * 256 + (size_t)c4 * 8];
      }
      float p[8];
#pragma unroll
      for (int i = 0; i < 8; i++) {
        half2v k01 = {kvmv[i][0], kvmv[i][1]}, k23 = {kvmv[i][2], kvmv[i][3]};
        float d = __builtin_amdgcn_fdot2(
            k01, q01, __builtin_amdgcn_fdot2(k23, q23, 0.f, false), false);
        d += __shfl_xor(d, 1);
        d += __shfl_xor(d, 2);
        p[i] = (e[i].x >= 0) ? d : -1e30f;
      }
      float nm = m;
#pragma unroll
      for (int i = 0; i < 8; i++) nm = fmaxf(nm, p[i]);
      float sc = __expf(m - nm);
      float t[8];
      float ssum = 0.f;
#pragma unroll
      for (int i = 0; i < 8; i++) {
        t[i] = __expf(p[i] - nm);
        ssum += t[i];
      }
      s = s * sc + ssum;
      a0 *= sc; a1 *= sc; a2 *= sc; a3 *= sc;
#pragma unroll
      for (int i = 0; i < 8; i++) {
        float w = (e[i].x >= 0) ? __int_as_float(e[i].y) : 0.f;
        float f = t[i] * w;
        a0 += f * (float)kvmv[i][4];
        a1 += f * (float)kvmv[i][5];
        a2 += f * (float)kvmv[i][6];
        a3 += f * (float)kvmv[i][7];
      }
      m = nm;
    }
    float mo = __shfl_xor(m, 32);
    float so = __shfl_xor(s, 32);
    float c0 = __shfl_xor(a0, 32), c1 = __shfl_xor(a1, 32);
    float c2 = __shfl_xor(a2, 32), c3 = __shfl_xor(a3, 32);
    float M = fmaxf(m, mo);
    float e1 = __expf(m - M), e2 = __expf(mo - M);
    float st = s * e1 + so * e2;
    float v0 = a0 * e1 + c0 * e2, v1 = a1 * e1 + c1 * e2;
    float v2 = a2 * e1 + c2 * e2, v3 = a3 * e1 + c3 * e2;
    float inv = (st > 0.f) ? 1.f / st : 0.f;
    if (hh == 0) {
      half4v out4;
      out4[0] = (_Float16)(v0 * inv);
      out4[1] = (_Float16)(v1 * inv);
      out4[2] = (_Float16)(v2 * inv);
      out4[3] = (_Float16)(v3 * inv);
      *(half4v*)&agg[packA(node, ch, 128)] = out4;
    }
  }
}

extern "C" void kernel_launch(void* const* d_in, const int* in_sizes, int n_in,
                              void* d_out, int out_size, void* d_ws, size_t ws_size,
                              hipStream_t stream) {
  const float* x        = (const float*)d_in[0];
  const int*   edge_src = (const int*)d_in[1];
  const int*   edge_dst = (const int*)d_in[2];
  const float* edge_w   = (const float*)d_in[3];
  const int*   pos_src  = (const int*)d_in[4];
  const int*   pos_dst  = (const int*)d_in[5];
  const int*   neg_src  = (const int*)d_in[6];
  const int*   neg_dst  = (const int*)d_in[7];
  const float* W_in     = (const float*)d_in[8];
  const float* b_in     = (const float*)d_in[9];
  const float* Wk       = (const float*)d_in[10];
  const float* Wq       = (const float*)d_in[11];
  const float* Wv       = (const float*)d_in[12];
  const float* att_w    = (const float*)d_in[13];
  const float* msg_w    = (const float*)d_in[14];
  const float* pri      = (const float*)d_in[15];
  const float* Wa       = (const float*)d_in[16];
  const float* skip     = (const float*)d_in[17];
  const float* W1       = (const float*)d_in[18];
  const float* b1       = (const float*)d_in[19];
  const float* W2       = (const float*)d_in[20];
  const float* b2       = (const float*)d_in[21];
  const float* W3       = (const float*)d_in[22];
  const float* b3       = (const float*)d_in[23];
  float* out = (float*)d_out;

  // ---- workspace layout (bytes), ~91 MB
  char* W = (char*)d_ws;
  _Float16*  qbuf   = (_Float16*)(W + 0);          // 12,800,000
  _Float16*  kwmv   = (_Float16*)(W + 12800000);   // 25,600,000
  _Float16*  hbuf   = (_Float16*)(W + 38400000);   // 12,800,000 (packed h)
  _Float16*  agg    = (_Float16*)(W + 51200000);   // 12,800,000
  _Float16*  Wint   = (_Float16*)(W + 64000000);   // 32,768
  _Float16*  Wcat   = (_Float16*)(W + 64032768);   // 294,912
  _Float16*  Waf    = (_Float16*)(W + 64327680);   // 98,304
  _Float16*  W1f    = (_Float16*)(W + 64425984);   // 16,384
  _Float16*  W2f    = (_Float16*)(W + 64442368);   // 8,192
  int2*      eld    = (int2*)(W + 64450560);       // 12,800,000 (padded-16 edges)
  int*       deg    = (int*)(W + 77250560);        // 200,000
  int*       poffs  = (int*)(W + 77450560);        // 200,016
  int*       cursor = (int*)(W + 77650576);        // 200,000
  int*       perm   = (int*)(W + 77850576);        // 200,000
  int*       bsum   = (int*)(W + 78050576);        // 1,024
  int*       boff   = (int*)(W + 78051600);        // 1,024
  int*       bh     = (int*)(W + 78052624);        // 1,024
  int*       bcur   = (int*)(W + 78053648);        // 1,024
  _Float16*  hrow   = (_Float16*)(W + 78054912);   // 12,800,000 (fp16 row-major hfinal)
  float* hfinal = out + 2 * N_PAIRS;

  hipMemsetAsync(deg, 0, N_NODES * sizeof(int), stream);
  hipMemsetAsync(bh, 0, 1024, stream);
  hipMemsetAsync(eld, 0xFF, 12800000, stream);  // sentinel: src=-1

  wprep_kernel<<<880, 256, 0, stream>>>(W_in, Wk, Wq, Wv, att_w, msg_w, pri, Wa, W1, W2,
                                        Wint, Wcat, Waf, W1f, W2f);
  hist_kernel<<<(N_EDGES + 255) / 256, 256, 0, stream>>>(edge_dst, deg, N_EDGES);
  scanA_kernel<<<196, 256, 0, stream>>>(deg, poffs, bsum, N_NODES);
  scanB_kernel<<<1, 256, 0, stream>>>(bsum, boff, poffs, 196, N_NODES);
  scanC_kernel<<<196, 256, 0, stream>>>(poffs, boff, cursor, N_NODES);
  scatter_kernel<<<(N_EDGES + 255) / 256, 256, 0, stream>>>(
      edge_src, edge_dst, edge_w, cursor, eld, N_EDGES);
  bhist_kernel<<<196, 256, 0, stream>>>(deg, bh, N_NODES);
  bscan_kernel<<<1, 256, 0, stream>>>(bh, bcur);
  bscatter_kernel<<<196, 256, 0, stream>>>(deg, bcur, perm, N_NODES);

  // layer 0: x -> h_in (relu proj) -> kqv0
  fused_layer<1><<<782, 256, 0, stream>>>(x, nullptr, Wint, b_in, nullptr, hbuf,
                                          Wcat, kwmv, qbuf, N_NODES);
  edge_agg_kernel<<<2048, 256, 0, stream>>>(kwmv, qbuf, poffs, eld, perm, agg, N_NODES);
  // layer 1: agg0 -> h0 (skip-mix+relu) -> kqv1
  fused_layer<0><<<782, 256, 0, stream>>>(nullptr, agg, Waf, nullptr, skip + 0, hbuf,
                                          Wcat + 49152, kwmv, qbuf, N_NODES);
  edge_agg_kernel<<<2048, 256, 0, stream>>>(kwmv, qbuf, poffs, eld, perm, agg, N_NODES);
  // layer 2: agg1 -> h1 (skip-mix+relu) -> kqv2
  fused_layer<0><<<782, 256, 0, stream>>>(nullptr, agg, Waf + 16384, nullptr, skip + 1,
                                          hbuf, Wcat + 98304, kwmv, qbuf, N_NODES);
  edge_agg_kernel<<<2048, 256, 0, stream>>>(kwmv, qbuf, poffs, eld, perm, agg, N_NODES);
  // final: agg2 -> hfinal (skip-mix, no relu) + hrow fp16
  gemm_last<<<782, 256, 0, stream>>>(agg, Waf + 32768, skip + 2, hbuf,
                                     hfinal, hrow, N_NODES);
  // predictor (fully fused)
  pred_fused<<<3125, 256, 0, stream>>>(hrow, pos_src, pos_dst, neg_src, neg_dst,
                                       W1f, b1, W2f, b2, W3, b3, out, 2 * N_PAIRS);
}